// Round 3
// baseline (657.607 us; speedup 1.0000x reference)
//
#include <hip/hip_runtime.h>
#include <hip/hip_fp16.h>
#include <math.h>

#define U_NUM 100000
#define I_NUM 50000
#define NE    2000000
#define EMB   64
#define NLAYERS 3

// bucketing: 512 rows per bucket
#define BSH   9
#define BROWS 512
#define NBU_U ((U_NUM + 511) >> 9)   // 196
#define NBU_I ((I_NUM + 511) >> 9)   // 98
#define NBU_T (NBU_U + NBU_I)        // 294
#define CHUNK 8192
#define NBLK_E ((NE + CHUNK - 1) / CHUNK)   // 245  (must stay <= 256 for colscan_k)
#define DBINS 512
#define PACK_SH 17
#define PACK_MASK 0x1FFFF

typedef float nf4 __attribute__((ext_vector_type(4)));   // nontemporal-legal float4

static inline int ceil_div(int a, int b){ return (a + b - 1) / b; }

// ---------------- phase 1: per-block bucket counts ----------------
// block 0/1 also zero the degree histograms (saves two memset launches)

__global__ void hist_k(const int* __restrict__ u_idx, const int* __restrict__ i_idx,
                       int* __restrict__ cm_u, int* __restrict__ cm_i,
                       int* __restrict__ dhist_u, int* __restrict__ dhist_i){
  if (blockIdx.x == 0){
    for (int t = threadIdx.x; t < DBINS; t += 256) dhist_u[t] = 0;
  } else if (blockIdx.x == 1){
    for (int t = threadIdx.x; t < DBINS; t += 256) dhist_i[t] = 0;
  }
  __shared__ int h[NBU_T];
  for (int t = threadIdx.x; t < NBU_T; t += 256) h[t] = 0;
  __syncthreads();
  int base = blockIdx.x * CHUNK;
  int end = min(base + CHUNK, NE);
  for (int e = base + (threadIdx.x << 1); e < end; e += 512){
    int2 uu = *(const int2*)(u_idx + e);
    int2 ii = *(const int2*)(i_idx + e);
    atomicAdd(&h[uu.x >> BSH], 1);
    atomicAdd(&h[uu.y >> BSH], 1);
    atomicAdd(&h[NBU_U + (ii.x >> BSH)], 1);
    atomicAdd(&h[NBU_U + (ii.y >> BSH)], 1);
  }
  __syncthreads();
  for (int t = threadIdx.x; t < NBU_U; t += 256) cm_u[blockIdx.x * NBU_U + t] = h[t];
  for (int t = threadIdx.x; t < NBU_I; t += 256) cm_i[blockIdx.x * NBU_I + t] = h[NBU_U + t];
}

// column sums of the count matrices -> per-bucket totals
__global__ void colsum_k(const int* __restrict__ cm_u, const int* __restrict__ cm_i,
                         int* __restrict__ tot_u, int* __restrict__ tot_i){
  __shared__ int s[256];
  int j = blockIdx.x;
  const int* cm; int* tot; int jj, stride;
  if (j < NBU_U){ cm = cm_u; tot = tot_u; jj = j; stride = NBU_U; }
  else { cm = cm_i; tot = tot_i; jj = j - NBU_U; stride = NBU_I; }
  int acc = 0;
  for (int b = threadIdx.x; b < NBLK_E; b += 256) acc += cm[b * stride + jj];
  s[threadIdx.x] = acc; __syncthreads();
  for (int o = 128; o > 0; o >>= 1){
    if (threadIdx.x < o) s[threadIdx.x] += s[threadIdx.x + o];
    __syncthreads();
  }
  if (threadIdx.x == 0) tot[jj] = s[0];
}

// paired single-block exclusive scans (block 0 -> set A, block 1 -> set B)
__global__ void small_scan2_k(const int* __restrict__ cA, int* __restrict__ oA,
                              int* __restrict__ rA, int nA,
                              const int* __restrict__ cB, int* __restrict__ oB,
                              int* __restrict__ rB, int nB){
  const int* cnt; int* offs; int* cur; int n;
  if (blockIdx.x == 0){ cnt = cA; offs = oA; cur = rA; n = nA; }
  else { cnt = cB; offs = oB; cur = rB; n = nB; }
  __shared__ int s[1024];
  int t = threadIdx.x;
  int v = (t < n) ? cnt[t] : 0;
  s[t] = v; __syncthreads();
  for (int o = 1; o < 1024; o <<= 1){
    int x = (t >= o) ? s[t - o] : 0;
    __syncthreads();
    s[t] += x;
    __syncthreads();
  }
  int excl = (t > 0) ? s[t - 1] : 0;
  if (t < n){ offs[t] = excl; cur[t] = excl; }
  if (t == n - 1) offs[n] = s[t];
}

// per-bucket column scan: basemat[b][j] = boffs[j] + sum_{b'<b} cm[b'][j]
__global__ void colscan_k(const int* __restrict__ cm_u, const int* __restrict__ cm_i,
                          const int* __restrict__ boffs_u, const int* __restrict__ boffs_i,
                          int* __restrict__ bm_u, int* __restrict__ bm_i){
  __shared__ int s[256];
  int j = blockIdx.x;
  const int* cm; const int* boffs; int* bm; int jj, stride;
  if (j < NBU_U){ cm = cm_u; boffs = boffs_u; bm = bm_u; jj = j; stride = NBU_U; }
  else { cm = cm_i; boffs = boffs_i; bm = bm_i; jj = j - NBU_U; stride = NBU_I; }
  int t = threadIdx.x;
  int v = (t < NBLK_E) ? cm[t * stride + jj] : 0;
  s[t] = v; __syncthreads();
  for (int o = 1; o < 256; o <<= 1){
    int x = (t >= o) ? s[t - o] : 0;
    __syncthreads();
    s[t] += x;
    __syncthreads();
  }
  int excl = (t > 0) ? s[t - 1] : 0;
  if (t < NBLK_E) bm[t * stride + jj] = excl + boffs[jj];
}

// ---------------- phase 2: scatter edges into bucket-sorted bins ----------------
// packed bin entry: (row_local << 17) | neighbor  (row_local < 512, neighbor < 2^17)

__global__ void binfill_k(const int* __restrict__ u_idx, const int* __restrict__ i_idx,
                          const int* __restrict__ bm_u, const int* __restrict__ bm_i,
                          int* __restrict__ bin_u, int* __restrict__ bin_i){
  __shared__ int cur[NBU_T];
  for (int t = threadIdx.x; t < NBU_U; t += 256) cur[t] = bm_u[blockIdx.x * NBU_U + t];
  for (int t = threadIdx.x; t < NBU_I; t += 256) cur[NBU_U + t] = bm_i[blockIdx.x * NBU_I + t];
  __syncthreads();
  int base = blockIdx.x * CHUNK;
  int end = min(base + CHUNK, NE);
  for (int e = base + (threadIdx.x << 1); e < end; e += 512){
    int2 uu = *(const int2*)(u_idx + e);
    int2 ii = *(const int2*)(i_idx + e);
    int p;
    p = atomicAdd(&cur[uu.x >> BSH], 1);            bin_u[p] = ((uu.x & 511) << PACK_SH) | ii.x;
    p = atomicAdd(&cur[uu.y >> BSH], 1);            bin_u[p] = ((uu.y & 511) << PACK_SH) | ii.y;
    p = atomicAdd(&cur[NBU_U + (ii.x >> BSH)], 1);  bin_i[p] = ((ii.x & 511) << PACK_SH) | uu.x;
    p = atomicAdd(&cur[NBU_U + (ii.y >> BSH)], 1);  bin_i[p] = ((ii.y & 511) << PACK_SH) | uu.y;
  }
}

// ---------------- phase 3: per-bucket CSR build (cnt/offs/norms/adj + LDS deg hist) ----------------

__global__ void bucket_build_k(const int* __restrict__ bin_u, const int* __restrict__ bin_i,
                               const int* __restrict__ boffs_u, const int* __restrict__ boffs_i,
                               int* __restrict__ cnt_u, int* __restrict__ cnt_i,
                               int* __restrict__ offs_u, int* __restrict__ offs_i,
                               float* __restrict__ du_inv, float* __restrict__ du_invs,
                               float* __restrict__ di_inv, float* __restrict__ di_invs,
                               int* __restrict__ adj_u, int* __restrict__ adj_i,
                               int* __restrict__ dhist_u, int* __restrict__ dhist_i){
  __shared__ int h[BROWS];
  __shared__ int part[256];
  __shared__ int dh[DBINS];
  int b = blockIdx.x;
  const int* bin; const int* boffs; int* cnt; int* offs; float* inv; float* invs;
  int* adj; int* dhist; int jj, nrows;
  if (b < NBU_U){
    bin = bin_u; boffs = boffs_u; cnt = cnt_u; offs = offs_u;
    inv = du_inv; invs = du_invs; adj = adj_u; dhist = dhist_u; jj = b; nrows = U_NUM;
  } else {
    bin = bin_i; boffs = boffs_i; cnt = cnt_i; offs = offs_i;
    inv = di_inv; invs = di_invs; adj = adj_i; dhist = dhist_i; jj = b - NBU_U; nrows = I_NUM;
  }
  int tid = threadIdx.x;
  int r0 = jj << BSH;
  int beg = boffs[jj], end = boffs[jj + 1];
  h[2*tid] = 0; h[2*tid + 1] = 0;
  for (int t = tid; t < DBINS; t += 256) dh[t] = 0;
  __syncthreads();
  for (int e = beg + tid; e < end; e += 256)
    atomicAdd(&h[((unsigned)bin[e]) >> PACK_SH], 1);
  __syncthreads();
  int c0 = h[2*tid], c1 = h[2*tid + 1];
  part[tid] = c0 + c1; __syncthreads();
  for (int o = 1; o < 256; o <<= 1){
    int x = (tid >= o) ? part[tid - o] : 0;
    __syncthreads();
    part[tid] += x;
    __syncthreads();
  }
  int excl = (tid > 0) ? part[tid - 1] : 0;
  h[2*tid] = excl;
  h[2*tid + 1] = excl + c0;
#pragma unroll
  for (int k = 0; k < 2; ++k){
    int l = 2*tid + k;
    int row = r0 + l;
    int c = k ? c1 : c0;
    int o = k ? (excl + c0) : excl;
    if (row < nrows){
      cnt[row] = c;
      offs[row] = beg + o;
      float d = (c > 0) ? (float)c : 1.0f;
      inv[row]  = 1.0f / d;
      invs[row] = 1.0f / sqrtf(d);
      atomicAdd(&dh[min(c, DBINS - 1)], 1);
    } else if (row == nrows){
      offs[row] = beg + o;   // global sentinel (== NE in the last bucket)
    }
  }
  __syncthreads();
  // scatter adj using h as cursors (bucket-local CSR layout)
  for (int e = beg + tid; e < end; e += 256){
    int v = bin[e];
    int slot = beg + atomicAdd(&h[((unsigned)v) >> PACK_SH], 1);
    adj[slot] = v & PACK_MASK;
  }
  __syncthreads();
  for (int t = tid; t < DBINS; t += 256) if (dh[t]) atomicAdd(&dhist[t], dh[t]);
}

// ---------------- degree sort (counting sort -> DESCENDING perm) ----------------

__global__ void deg_scatter_k(const int* __restrict__ cnt, int* __restrict__ dcur,
                              int* __restrict__ perm, int n){
  __shared__ int h[DBINS];
  __shared__ int base_s[DBINS];
  for (int t = threadIdx.x; t < DBINS; t += 256) h[t] = 0;
  __syncthreads();
  int base = blockIdx.x * 2048;
  int end = min(base + 2048, n);
  for (int r = base + threadIdx.x; r < end; r += 256)
    atomicAdd(&h[min(cnt[r], DBINS - 1)], 1);
  __syncthreads();
  for (int t = threadIdx.x; t < DBINS; t += 256){
    int c = h[t];
    base_s[t] = c ? atomicAdd(&dcur[t], c) : 0;
    h[t] = 0;
  }
  __syncthreads();
  for (int r = base + threadIdx.x; r < end; r += 256){
    int b = min(cnt[r], DBINS - 1);
    int pos = base_s[b] + atomicAdd(&h[b], 1);
    perm[n - 1 - pos] = r;   // descending degree: stragglers dispatch first
  }
}

// ---------------- fused init: out = 0.25*emb ; half tables = emb * pre-scale ----------------

__global__ void init_k(const float* __restrict__ ue, const float* __restrict__ ie,
                       const float* __restrict__ dus, const float* __restrict__ dis,
                       float* __restrict__ out, __half* __restrict__ ue_h,
                       __half* __restrict__ ie_h){
  int idx4 = blockIdx.x * blockDim.x + threadIdx.x;   // one float4 per thread
  const int nu4 = U_NUM * (EMB / 4);
  const int tot4 = (U_NUM + I_NUM) * (EMB / 4);
  if (idx4 >= tot4) return;
  const float* e; __half* hp; float s; int loc;
  if (idx4 < nu4){ e = ue; hp = ue_h; loc = idx4; s = dus[idx4 >> 4]; }
  else { e = ie; hp = ie_h; loc = idx4 - nu4; s = dis[(idx4 - nu4) >> 4]; }
  float4 v = ((const float4*)e)[loc];
  float4 o = make_float4(v.x * 0.25f, v.y * 0.25f, v.z * 0.25f, v.w * 0.25f);
  ((float4*)out)[idx4] = o;
  __half2 h01 = __floats2half2_rn(v.x * s, v.y * s);
  __half2 h23 = __floats2half2_rn(v.z * s, v.w * s);
  ((__half2*)hp)[loc * 2]     = h01;
  ((__half2*)hp)[loc * 2 + 1] = h23;
}

// ---------------- fp16 gather SpMM, paired (two independent SpMMs per launch) ----------------
// 8 lanes per row, each lane owns 8 halves (16 B) -> one float4 gather per edge
// per lane. Software-pipelined: iteration g consumes the adj indices preloaded
// at iteration g-1 and issues the NEXT group's adj loads alongside the current
// gathers -> one exposed memory latency per 8 edges instead of two. adj and
// the sum RMW are nontemporal (read/written once per launch) so they don't
// evict gather-table lines from L2. perm is degree-DESCENDING.

__device__ __forceinline__ void acc8(float* a, float4 v){
  union { float4 f; __half2 h[4]; } u;
  u.f = v;
#pragma unroll
  for (int k = 0; k < 4; ++k){
    float2 f = __half22float2(u.h[k]);
    a[2*k]     += f.x;
    a[2*k + 1] += f.y;
  }
}

template<bool HAS_SUM>
__global__ void spmm_pair(
    const int* __restrict__ offsA, const int* __restrict__ adjA, const int* __restrict__ permA,
    const __half* __restrict__ srcA, const float* __restrict__ psA, const float* __restrict__ phA,
    __half* __restrict__ dstA, float* __restrict__ sumA, int nA,
    const int* __restrict__ offsB, const int* __restrict__ adjB, const int* __restrict__ permB,
    const __half* __restrict__ srcB, const float* __restrict__ psB, const float* __restrict__ phB,
    __half* __restrict__ dstB, float* __restrict__ sumB, int nB){
  int t = blockIdx.x * blockDim.x + threadIdx.x;
  int rid = t >> 3;
  int lane = t & 7;
  const int* offs; const int* adj; const __half* src; const float* ps; const float* ph;
  __half* dst; float* sum; int row;
  if (rid < nA){
    row = permA[rid]; offs = offsA; adj = adjA; src = srcA; ps = psA; ph = phA; dst = dstA; sum = sumA;
  } else {
    rid -= nA;
    if (rid >= nB) return;
    row = permB[rid]; offs = offsB; adj = adjB; src = srcB; ps = psB; ph = phB; dst = dstB; sum = sumB;
  }
  int beg = offs[row], end = offs[row + 1];
  const __half* sp8 = src + (size_t)(lane << 3);   // lane's 16 B slice base
  float acc[8];
#pragma unroll
  for (int k = 0; k < 8; ++k) acc[k] = 0.f;

  int nfull = (end - beg) >> 3;
  int j = beg + (nfull << 3);          // tail start
  if (nfull > 0){
    int p = beg;
    int n0 = __builtin_nontemporal_load(adj + p);
    int n1 = __builtin_nontemporal_load(adj + p + 1);
    int n2 = __builtin_nontemporal_load(adj + p + 2);
    int n3 = __builtin_nontemporal_load(adj + p + 3);
    int n4 = __builtin_nontemporal_load(adj + p + 4);
    int n5 = __builtin_nontemporal_load(adj + p + 5);
    int n6 = __builtin_nontemporal_load(adj + p + 6);
    int n7 = __builtin_nontemporal_load(adj + p + 7);
    p += 8;
    for (int g = 1; g < nfull; ++g, p += 8){
      float4 a0 = *(const float4*)(sp8 + (((size_t)n0) << 6));
      float4 a1 = *(const float4*)(sp8 + (((size_t)n1) << 6));
      float4 a2 = *(const float4*)(sp8 + (((size_t)n2) << 6));
      float4 a3 = *(const float4*)(sp8 + (((size_t)n3) << 6));
      float4 a4 = *(const float4*)(sp8 + (((size_t)n4) << 6));
      float4 a5 = *(const float4*)(sp8 + (((size_t)n5) << 6));
      float4 a6 = *(const float4*)(sp8 + (((size_t)n6) << 6));
      float4 a7 = *(const float4*)(sp8 + (((size_t)n7) << 6));
      int m0 = __builtin_nontemporal_load(adj + p);
      int m1 = __builtin_nontemporal_load(adj + p + 1);
      int m2 = __builtin_nontemporal_load(adj + p + 2);
      int m3 = __builtin_nontemporal_load(adj + p + 3);
      int m4 = __builtin_nontemporal_load(adj + p + 4);
      int m5 = __builtin_nontemporal_load(adj + p + 5);
      int m6 = __builtin_nontemporal_load(adj + p + 6);
      int m7 = __builtin_nontemporal_load(adj + p + 7);
      acc8(acc, a0); acc8(acc, a1); acc8(acc, a2); acc8(acc, a3);
      acc8(acc, a4); acc8(acc, a5); acc8(acc, a6); acc8(acc, a7);
      n0 = m0; n1 = m1; n2 = m2; n3 = m3;
      n4 = m4; n5 = m5; n6 = m6; n7 = m7;
    }
    float4 a0 = *(const float4*)(sp8 + (((size_t)n0) << 6));
    float4 a1 = *(const float4*)(sp8 + (((size_t)n1) << 6));
    float4 a2 = *(const float4*)(sp8 + (((size_t)n2) << 6));
    float4 a3 = *(const float4*)(sp8 + (((size_t)n3) << 6));
    float4 a4 = *(const float4*)(sp8 + (((size_t)n4) << 6));
    float4 a5 = *(const float4*)(sp8 + (((size_t)n5) << 6));
    float4 a6 = *(const float4*)(sp8 + (((size_t)n6) << 6));
    float4 a7 = *(const float4*)(sp8 + (((size_t)n7) << 6));
    acc8(acc, a0); acc8(acc, a1); acc8(acc, a2); acc8(acc, a3);
    acc8(acc, a4); acc8(acc, a5); acc8(acc, a6); acc8(acc, a7);
  }
  for (; j < end; ++j){
    int n0 = adj[j];
    float4 a0 = *(const float4*)(sp8 + (((size_t)n0) << 6));
    acc8(acc, a0);
  }
  float phv = ph[row];
  union { float4 f; __half2 h[4]; } ob;
#pragma unroll
  for (int k = 0; k < 4; ++k)
    ob.h[k] = __floats2half2_rn(acc[2*k] * phv, acc[2*k + 1] * phv);
  *(float4*)(dst + (((size_t)row) << 6) + (size_t)(lane << 3)) = ob.f;
  if (HAS_SUM){
    float psv = ps[row] * 0.25f;
    nf4* sp = (nf4*)(sum + (((size_t)row) << 6) + (size_t)(lane << 3));
#pragma unroll
    for (int k = 0; k < 2; ++k){
      nf4 s = __builtin_nontemporal_load(sp + k);
      s.x += acc[4*k]     * psv;
      s.y += acc[4*k + 1] * psv;
      s.z += acc[4*k + 2] * psv;
      s.w += acc[4*k + 3] * psv;
      __builtin_nontemporal_store(s, sp + k);
    }
  }
}

// ---------------- driver ----------------

extern "C" void kernel_launch(void* const* d_in, const int* in_sizes, int n_in,
                              void* d_out, int out_size, void* d_ws, size_t ws_size,
                              hipStream_t stream){
  const float* user_emb = (const float*)d_in[0];
  const float* item_emb = (const float*)d_in[1];
  const int*   u_idx    = (const int*)d_in[2];
  const int*   i_idx    = (const int*)d_in[3];
  float* out = (float*)d_out;

  char* w = (char*)d_ws;
  size_t off = 0;
  auto alloc = [&](size_t bytes) -> void* {
    void* p = (void*)(w + off);
    off += (bytes + 255) & ~(size_t)255;
    return p;
  };
  int* cnt_u   = (int*)alloc((size_t)U_NUM * 4);
  int* cnt_i   = (int*)alloc((size_t)I_NUM * 4);
  int* offs_u  = (int*)alloc((size_t)(U_NUM + 1) * 4);
  int* offs_i  = (int*)alloc((size_t)(I_NUM + 1) * 4);
  int* cm_u    = (int*)alloc((size_t)NBLK_E * NBU_U * 4);
  int* cm_i    = (int*)alloc((size_t)NBLK_E * NBU_I * 4);
  int* bm_u    = (int*)alloc((size_t)NBLK_E * NBU_U * 4);
  int* bm_i    = (int*)alloc((size_t)NBLK_E * NBU_I * 4);
  int* tot_u   = (int*)alloc((size_t)NBU_U * 4);
  int* tot_i   = (int*)alloc((size_t)NBU_I * 4);
  int* boffs_u = (int*)alloc((size_t)(NBU_U + 1) * 4);
  int* boffs_i = (int*)alloc((size_t)(NBU_I + 1) * 4);
  int* scr_u   = (int*)alloc((size_t)NBU_U * 4);     // small_scan cur scratch
  int* scr_i   = (int*)alloc((size_t)NBU_I * 4);
  int* dhist_u = (int*)alloc((size_t)DBINS * 4);
  int* dhist_i = (int*)alloc((size_t)DBINS * 4);
  int* doffs_u = (int*)alloc((size_t)(DBINS + 1) * 4);
  int* doffs_i = (int*)alloc((size_t)(DBINS + 1) * 4);
  int* dcur_u  = (int*)alloc((size_t)DBINS * 4);
  int* dcur_i  = (int*)alloc((size_t)DBINS * 4);
  int* perm_u  = (int*)alloc((size_t)U_NUM * 4);
  int* perm_i  = (int*)alloc((size_t)I_NUM * 4);
  int* adj_u   = (int*)alloc((size_t)NE * 4);
  int* adj_i   = (int*)alloc((size_t)NE * 4);
  float* du_inv  = (float*)alloc((size_t)U_NUM * 4);
  float* du_invs = (float*)alloc((size_t)U_NUM * 4);
  float* di_inv  = (float*)alloc((size_t)I_NUM * 4);
  float* di_invs = (float*)alloc((size_t)I_NUM * 4);
  // half-table region, 38.4 MB; the packed bins (16 MB) alias its start and
  // are dead before init_k writes the half tables.
  __half* hreg = (__half*)alloc((size_t)(U_NUM + I_NUM) * 2 * EMB * 2);
  __half* ue_h    = hreg;                                  // U_NUM*64
  __half* ie_h    = ue_h    + (size_t)U_NUM * EMB;         // I_NUM*64
  __half* tmp_i_h = ie_h    + (size_t)I_NUM * EMB;         // I_NUM*64
  __half* tmp_u_h = tmp_i_h + (size_t)I_NUM * EMB;         // U_NUM*64
  int* bin_u = (int*)hreg;            // NE ints (8 MB)
  int* bin_i = bin_u + NE;            // NE ints (8 MB)

  // ---- CSR build (count-matrix radix sort) ----
  hist_k<<<NBLK_E, 256, 0, stream>>>(u_idx, i_idx, cm_u, cm_i, dhist_u, dhist_i);
  colsum_k<<<NBU_T, 256, 0, stream>>>(cm_u, cm_i, tot_u, tot_i);
  small_scan2_k<<<2, 1024, 0, stream>>>(tot_u, boffs_u, scr_u, NBU_U,
                                        tot_i, boffs_i, scr_i, NBU_I);
  colscan_k<<<NBU_T, 256, 0, stream>>>(cm_u, cm_i, boffs_u, boffs_i, bm_u, bm_i);
  binfill_k<<<NBLK_E, 256, 0, stream>>>(u_idx, i_idx, bm_u, bm_i, bin_u, bin_i);
  bucket_build_k<<<NBU_T, 256, 0, stream>>>(bin_u, bin_i, boffs_u, boffs_i,
                                            cnt_u, cnt_i, offs_u, offs_i,
                                            du_inv, du_invs, di_inv, di_invs,
                                            adj_u, adj_i, dhist_u, dhist_i);

  // ---- degree sort (descending perm) ----
  small_scan2_k<<<2, 1024, 0, stream>>>(dhist_u, doffs_u, dcur_u, DBINS,
                                        dhist_i, doffs_i, dcur_i, DBINS);
  deg_scatter_k<<<ceil_div(U_NUM, 2048), 256, 0, stream>>>(cnt_u, dcur_u, perm_u, U_NUM);
  deg_scatter_k<<<ceil_div(I_NUM, 2048), 256, 0, stream>>>(cnt_i, dcur_i, perm_i, I_NUM);

  // ---- propagation (fp16 tables, fp32 accumulation) ----
  init_k<<<ceil_div((U_NUM + I_NUM) * EMB / 4, 256), 256, 0, stream>>>(
      user_emb, item_emb, du_invs, di_invs, out, ue_h, ie_h);

  float* sum_u = out;
  float* sum_i = out + (size_t)U_NUM * EMB;
  const int pair_grid = ceil_div((U_NUM + I_NUM) * 8, 256);
  for (int l = 0; l < NLAYERS; ++l){
    // A: tmp_i_h = half(d_i_inv * R^T ue_h)   +   C: tmp_u_h = half(d_u_inv * R ie_h)
    spmm_pair<false><<<pair_grid, 256, 0, stream>>>(
        offs_i, adj_i, perm_i, ue_h, nullptr, di_inv, tmp_i_h, nullptr, I_NUM,
        offs_u, adj_u, perm_u, ie_h, nullptr, du_inv, tmp_u_h, nullptr, U_NUM);
    // B: sum_u += 0.25*du_invs * R tmp_i_h ; ue_h = half(du_inv * R tmp_i_h)
    // D: sum_i += 0.25*di_invs * R^T tmp_u_h ; ie_h = half(di_inv * R^T tmp_u_h)
    spmm_pair<true><<<pair_grid, 256, 0, stream>>>(
        offs_u, adj_u, perm_u, tmp_i_h, du_invs, du_inv, ue_h, sum_u, U_NUM,
        offs_i, adj_i, perm_i, tmp_u_h, di_invs, di_inv, ie_h, sum_i, I_NUM);
  }
}

// Round 4
// 613.532 us; speedup vs baseline: 1.0718x; 1.0718x over previous
//
#include <hip/hip_runtime.h>
#include <hip/hip_fp16.h>
#include <math.h>

#define U_NUM 100000
#define I_NUM 50000
#define NE    2000000
#define EMB   64
#define NLAYERS 3

// bucketing: 512 rows per bucket
#define BSH   9
#define BROWS 512
#define NBU_U ((U_NUM + 511) >> 9)   // 196
#define NBU_I ((I_NUM + 511) >> 9)   // 98
#define NBU_T (NBU_U + NBU_I)        // 294
#define CHUNK 8192
#define NBLK_E ((NE + CHUNK - 1) / CHUNK)   // 245  (must stay <= 256 for colscan_k)
#define DBINS 512
#define PACK_SH 17
#define PACK_MASK 0x1FFFF

static inline int ceil_div(int a, int b){ return (a + b - 1) / b; }

// ---------------- phase 1: per-block bucket counts ----------------
// block 0/1 also zero the degree histograms (saves two memset launches)

__global__ void hist_k(const int* __restrict__ u_idx, const int* __restrict__ i_idx,
                       int* __restrict__ cm_u, int* __restrict__ cm_i,
                       int* __restrict__ dhist_u, int* __restrict__ dhist_i){
  if (blockIdx.x == 0){
    for (int t = threadIdx.x; t < DBINS; t += 256) dhist_u[t] = 0;
  } else if (blockIdx.x == 1){
    for (int t = threadIdx.x; t < DBINS; t += 256) dhist_i[t] = 0;
  }
  __shared__ int h[NBU_T];
  for (int t = threadIdx.x; t < NBU_T; t += 256) h[t] = 0;
  __syncthreads();
  int base = blockIdx.x * CHUNK;
  int end = min(base + CHUNK, NE);
  for (int e = base + (threadIdx.x << 1); e < end; e += 512){
    int2 uu = *(const int2*)(u_idx + e);
    int2 ii = *(const int2*)(i_idx + e);
    atomicAdd(&h[uu.x >> BSH], 1);
    atomicAdd(&h[uu.y >> BSH], 1);
    atomicAdd(&h[NBU_U + (ii.x >> BSH)], 1);
    atomicAdd(&h[NBU_U + (ii.y >> BSH)], 1);
  }
  __syncthreads();
  for (int t = threadIdx.x; t < NBU_U; t += 256) cm_u[blockIdx.x * NBU_U + t] = h[t];
  for (int t = threadIdx.x; t < NBU_I; t += 256) cm_i[blockIdx.x * NBU_I + t] = h[NBU_U + t];
}

// column sums of the count matrices -> per-bucket totals
__global__ void colsum_k(const int* __restrict__ cm_u, const int* __restrict__ cm_i,
                         int* __restrict__ tot_u, int* __restrict__ tot_i){
  __shared__ int s[256];
  int j = blockIdx.x;
  const int* cm; int* tot; int jj, stride;
  if (j < NBU_U){ cm = cm_u; tot = tot_u; jj = j; stride = NBU_U; }
  else { cm = cm_i; tot = tot_i; jj = j - NBU_U; stride = NBU_I; }
  int acc = 0;
  for (int b = threadIdx.x; b < NBLK_E; b += 256) acc += cm[b * stride + jj];
  s[threadIdx.x] = acc; __syncthreads();
  for (int o = 128; o > 0; o >>= 1){
    if (threadIdx.x < o) s[threadIdx.x] += s[threadIdx.x + o];
    __syncthreads();
  }
  if (threadIdx.x == 0) tot[jj] = s[0];
}

// paired single-block exclusive scans (block 0 -> set A, block 1 -> set B)
__global__ void small_scan2_k(const int* __restrict__ cA, int* __restrict__ oA,
                              int* __restrict__ rA, int nA,
                              const int* __restrict__ cB, int* __restrict__ oB,
                              int* __restrict__ rB, int nB){
  const int* cnt; int* offs; int* cur; int n;
  if (blockIdx.x == 0){ cnt = cA; offs = oA; cur = rA; n = nA; }
  else { cnt = cB; offs = oB; cur = rB; n = nB; }
  __shared__ int s[1024];
  int t = threadIdx.x;
  int v = (t < n) ? cnt[t] : 0;
  s[t] = v; __syncthreads();
  for (int o = 1; o < 1024; o <<= 1){
    int x = (t >= o) ? s[t - o] : 0;
    __syncthreads();
    s[t] += x;
    __syncthreads();
  }
  int excl = (t > 0) ? s[t - 1] : 0;
  if (t < n){ offs[t] = excl; cur[t] = excl; }
  if (t == n - 1) offs[n] = s[t];
}

// per-bucket column scan: basemat[b][j] = boffs[j] + sum_{b'<b} cm[b'][j]
__global__ void colscan_k(const int* __restrict__ cm_u, const int* __restrict__ cm_i,
                          const int* __restrict__ boffs_u, const int* __restrict__ boffs_i,
                          int* __restrict__ bm_u, int* __restrict__ bm_i){
  __shared__ int s[256];
  int j = blockIdx.x;
  const int* cm; const int* boffs; int* bm; int jj, stride;
  if (j < NBU_U){ cm = cm_u; boffs = boffs_u; bm = bm_u; jj = j; stride = NBU_U; }
  else { cm = cm_i; boffs = boffs_i; bm = bm_i; jj = j - NBU_U; stride = NBU_I; }
  int t = threadIdx.x;
  int v = (t < NBLK_E) ? cm[t * stride + jj] : 0;
  s[t] = v; __syncthreads();
  for (int o = 1; o < 256; o <<= 1){
    int x = (t >= o) ? s[t - o] : 0;
    __syncthreads();
    s[t] += x;
    __syncthreads();
  }
  int excl = (t > 0) ? s[t - 1] : 0;
  if (t < NBLK_E) bm[t * stride + jj] = excl + boffs[jj];
}

// ---------------- phase 2: scatter edges into bucket-sorted bins ----------------
// packed bin entry: (row_local << 17) | neighbor  (row_local < 512, neighbor < 2^17)

__global__ void binfill_k(const int* __restrict__ u_idx, const int* __restrict__ i_idx,
                          const int* __restrict__ bm_u, const int* __restrict__ bm_i,
                          int* __restrict__ bin_u, int* __restrict__ bin_i){
  __shared__ int cur[NBU_T];
  for (int t = threadIdx.x; t < NBU_U; t += 256) cur[t] = bm_u[blockIdx.x * NBU_U + t];
  for (int t = threadIdx.x; t < NBU_I; t += 256) cur[NBU_U + t] = bm_i[blockIdx.x * NBU_I + t];
  __syncthreads();
  int base = blockIdx.x * CHUNK;
  int end = min(base + CHUNK, NE);
  for (int e = base + (threadIdx.x << 1); e < end; e += 512){
    int2 uu = *(const int2*)(u_idx + e);
    int2 ii = *(const int2*)(i_idx + e);
    int p;
    p = atomicAdd(&cur[uu.x >> BSH], 1);            bin_u[p] = ((uu.x & 511) << PACK_SH) | ii.x;
    p = atomicAdd(&cur[uu.y >> BSH], 1);            bin_u[p] = ((uu.y & 511) << PACK_SH) | ii.y;
    p = atomicAdd(&cur[NBU_U + (ii.x >> BSH)], 1);  bin_i[p] = ((ii.x & 511) << PACK_SH) | uu.x;
    p = atomicAdd(&cur[NBU_U + (ii.y >> BSH)], 1);  bin_i[p] = ((ii.y & 511) << PACK_SH) | uu.y;
  }
}

// ---------------- phase 3: per-bucket CSR build (cnt/offs/norms/adj + LDS deg hist) ----------------

__global__ void bucket_build_k(const int* __restrict__ bin_u, const int* __restrict__ bin_i,
                               const int* __restrict__ boffs_u, const int* __restrict__ boffs_i,
                               int* __restrict__ cnt_u, int* __restrict__ cnt_i,
                               int* __restrict__ offs_u, int* __restrict__ offs_i,
                               float* __restrict__ du_inv, float* __restrict__ du_invs,
                               float* __restrict__ di_inv, float* __restrict__ di_invs,
                               int* __restrict__ adj_u, int* __restrict__ adj_i,
                               int* __restrict__ dhist_u, int* __restrict__ dhist_i){
  __shared__ int h[BROWS];
  __shared__ int part[256];
  __shared__ int dh[DBINS];
  int b = blockIdx.x;
  const int* bin; const int* boffs; int* cnt; int* offs; float* inv; float* invs;
  int* adj; int* dhist; int jj, nrows;
  if (b < NBU_U){
    bin = bin_u; boffs = boffs_u; cnt = cnt_u; offs = offs_u;
    inv = du_inv; invs = du_invs; adj = adj_u; dhist = dhist_u; jj = b; nrows = U_NUM;
  } else {
    bin = bin_i; boffs = boffs_i; cnt = cnt_i; offs = offs_i;
    inv = di_inv; invs = di_invs; adj = adj_i; dhist = dhist_i; jj = b - NBU_U; nrows = I_NUM;
  }
  int tid = threadIdx.x;
  int r0 = jj << BSH;
  int beg = boffs[jj], end = boffs[jj + 1];
  h[2*tid] = 0; h[2*tid + 1] = 0;
  for (int t = tid; t < DBINS; t += 256) dh[t] = 0;
  __syncthreads();
  for (int e = beg + tid; e < end; e += 256)
    atomicAdd(&h[((unsigned)bin[e]) >> PACK_SH], 1);
  __syncthreads();
  int c0 = h[2*tid], c1 = h[2*tid + 1];
  part[tid] = c0 + c1; __syncthreads();
  for (int o = 1; o < 256; o <<= 1){
    int x = (tid >= o) ? part[tid - o] : 0;
    __syncthreads();
    part[tid] += x;
    __syncthreads();
  }
  int excl = (tid > 0) ? part[tid - 1] : 0;
  h[2*tid] = excl;
  h[2*tid + 1] = excl + c0;
#pragma unroll
  for (int k = 0; k < 2; ++k){
    int l = 2*tid + k;
    int row = r0 + l;
    int c = k ? c1 : c0;
    int o = k ? (excl + c0) : excl;
    if (row < nrows){
      cnt[row] = c;
      offs[row] = beg + o;
      float d = (c > 0) ? (float)c : 1.0f;
      inv[row]  = 1.0f / d;
      invs[row] = 1.0f / sqrtf(d);
      atomicAdd(&dh[min(c, DBINS - 1)], 1);
    } else if (row == nrows){
      offs[row] = beg + o;   // global sentinel (== NE in the last bucket)
    }
  }
  __syncthreads();
  // scatter adj using h as cursors (bucket-local CSR layout)
  for (int e = beg + tid; e < end; e += 256){
    int v = bin[e];
    int slot = beg + atomicAdd(&h[((unsigned)v) >> PACK_SH], 1);
    adj[slot] = v & PACK_MASK;
  }
  __syncthreads();
  for (int t = tid; t < DBINS; t += 256) if (dh[t]) atomicAdd(&dhist[t], dh[t]);
}

// ---------------- degree sort (counting sort -> DESCENDING row descriptors) ----------------
// rd[rid] = {beg, end, row, 0}: one 16-B load in the SpMM replaces the
// perm[rid] -> offs[row] dependent-load chain (removes one serial latency).

__global__ void deg_scatter_k(const int* __restrict__ cnt, const int* __restrict__ offs,
                              int* __restrict__ dcur, int4* __restrict__ rd, int n){
  __shared__ int h[DBINS];
  __shared__ int base_s[DBINS];
  for (int t = threadIdx.x; t < DBINS; t += 256) h[t] = 0;
  __syncthreads();
  int base = blockIdx.x * 2048;
  int end = min(base + 2048, n);
  for (int r = base + threadIdx.x; r < end; r += 256)
    atomicAdd(&h[min(cnt[r], DBINS - 1)], 1);
  __syncthreads();
  for (int t = threadIdx.x; t < DBINS; t += 256){
    int c = h[t];
    base_s[t] = c ? atomicAdd(&dcur[t], c) : 0;
    h[t] = 0;
  }
  __syncthreads();
  for (int r = base + threadIdx.x; r < end; r += 256){
    int c = cnt[r];
    int b = min(c, DBINS - 1);
    int pos = base_s[b] + atomicAdd(&h[b], 1);
    int bg = offs[r];
    rd[n - 1 - pos] = make_int4(bg, bg + c, r, 0);   // descending degree
  }
}

// ---------------- fused init: out = 0.25*emb ; half tables = emb * pre-scale ----------------

__global__ void init_k(const float* __restrict__ ue, const float* __restrict__ ie,
                       const float* __restrict__ dus, const float* __restrict__ dis,
                       float* __restrict__ out, __half* __restrict__ ue_h,
                       __half* __restrict__ ie_h){
  int idx4 = blockIdx.x * blockDim.x + threadIdx.x;   // one float4 per thread
  const int nu4 = U_NUM * (EMB / 4);
  const int tot4 = (U_NUM + I_NUM) * (EMB / 4);
  if (idx4 >= tot4) return;
  const float* e; __half* hp; float s; int loc;
  if (idx4 < nu4){ e = ue; hp = ue_h; loc = idx4; s = dus[idx4 >> 4]; }
  else { e = ie; hp = ie_h; loc = idx4 - nu4; s = dis[(idx4 - nu4) >> 4]; }
  float4 v = ((const float4*)e)[loc];
  float4 o = make_float4(v.x * 0.25f, v.y * 0.25f, v.z * 0.25f, v.w * 0.25f);
  ((float4*)out)[idx4] = o;
  __half2 h01 = __floats2half2_rn(v.x * s, v.y * s);
  __half2 h23 = __floats2half2_rn(v.z * s, v.w * s);
  ((__half2*)hp)[loc * 2]     = h01;
  ((__half2*)hp)[loc * 2 + 1] = h23;
}

// ---------------- fp16 gather SpMM, paired (two independent SpMMs per launch) ----------------
// 8 lanes per row, each lane owns 8 halves (16 B) -> one float4 gather per edge
// per lane, fully contiguous per-row coverage per instruction. Row descriptor
// rd[rid] = {beg,end,row} is a single 16-B load (no perm->offs chain).
// Compiler-scheduled unroll x8 (manual rotation regressed: VGPR 48->56,
// occupancy 44->35% -- R3 post-mortem). rd is degree-DESCENDING.
// Epilogue: dst_h[row] = half(acc * post_h[row]); if HAS_SUM:
//   sum[row] += acc * post_sum[row] * 0.25   (final averaging folded in)

__device__ __forceinline__ void acc8(float* a, float4 v){
  union { float4 f; __half2 h[4]; } u;
  u.f = v;
#pragma unroll
  for (int k = 0; k < 4; ++k){
    float2 f = __half22float2(u.h[k]);
    a[2*k]     += f.x;
    a[2*k + 1] += f.y;
  }
}

template<bool HAS_SUM>
__global__ void spmm_pair(
    const int4* __restrict__ rdA, const int* __restrict__ adjA,
    const __half* __restrict__ srcA, const float* __restrict__ psA, const float* __restrict__ phA,
    __half* __restrict__ dstA, float* __restrict__ sumA, int nA,
    const int4* __restrict__ rdB, const int* __restrict__ adjB,
    const __half* __restrict__ srcB, const float* __restrict__ psB, const float* __restrict__ phB,
    __half* __restrict__ dstB, float* __restrict__ sumB, int nB){
  int t = blockIdx.x * blockDim.x + threadIdx.x;
  int rid = t >> 3;
  int lane = t & 7;
  const int4* rd; const int* adj; const __half* src; const float* ps; const float* ph;
  __half* dst; float* sum;
  if (rid < nA){
    rd = rdA; adj = adjA; src = srcA; ps = psA; ph = phA; dst = dstA; sum = sumA;
  } else {
    rid -= nA;
    if (rid >= nB) return;
    rd = rdB; adj = adjB; src = srcB; ps = psB; ph = phB; dst = dstB; sum = sumB;
  }
  int4 d = rd[rid];
  int beg = d.x, end = d.y, row = d.z;
  const __half* sp8 = src + (size_t)(lane << 3);   // lane's 16 B slice base
  float acc[8];
#pragma unroll
  for (int k = 0; k < 8; ++k) acc[k] = 0.f;
  int j = beg;
  for (; j + 7 < end; j += 8){
    int n0 = adj[j],   n1 = adj[j+1], n2 = adj[j+2], n3 = adj[j+3];
    int n4 = adj[j+4], n5 = adj[j+5], n6 = adj[j+6], n7 = adj[j+7];
    float4 a0 = *(const float4*)(sp8 + (((size_t)n0) << 6));
    float4 a1 = *(const float4*)(sp8 + (((size_t)n1) << 6));
    float4 a2 = *(const float4*)(sp8 + (((size_t)n2) << 6));
    float4 a3 = *(const float4*)(sp8 + (((size_t)n3) << 6));
    float4 a4 = *(const float4*)(sp8 + (((size_t)n4) << 6));
    float4 a5 = *(const float4*)(sp8 + (((size_t)n5) << 6));
    float4 a6 = *(const float4*)(sp8 + (((size_t)n6) << 6));
    float4 a7 = *(const float4*)(sp8 + (((size_t)n7) << 6));
    acc8(acc, a0); acc8(acc, a1); acc8(acc, a2); acc8(acc, a3);
    acc8(acc, a4); acc8(acc, a5); acc8(acc, a6); acc8(acc, a7);
  }
  for (; j < end; ++j){
    int n0 = adj[j];
    float4 a0 = *(const float4*)(sp8 + (((size_t)n0) << 6));
    acc8(acc, a0);
  }
  float phv = ph[row];
  union { float4 f; __half2 h[4]; } ob;
#pragma unroll
  for (int k = 0; k < 4; ++k)
    ob.h[k] = __floats2half2_rn(acc[2*k] * phv, acc[2*k + 1] * phv);
  *(float4*)(dst + (((size_t)row) << 6) + (size_t)(lane << 3)) = ob.f;
  if (HAS_SUM){
    float psv = ps[row] * 0.25f;
    float4* sp = (float4*)(sum + (((size_t)row) << 6) + (size_t)(lane << 3));
#pragma unroll
    for (int k = 0; k < 2; ++k){
      float4 s = sp[k];
      s.x += acc[4*k]     * psv;
      s.y += acc[4*k + 1] * psv;
      s.z += acc[4*k + 2] * psv;
      s.w += acc[4*k + 3] * psv;
      sp[k] = s;
    }
  }
}

// ---------------- driver ----------------

extern "C" void kernel_launch(void* const* d_in, const int* in_sizes, int n_in,
                              void* d_out, int out_size, void* d_ws, size_t ws_size,
                              hipStream_t stream){
  const float* user_emb = (const float*)d_in[0];
  const float* item_emb = (const float*)d_in[1];
  const int*   u_idx    = (const int*)d_in[2];
  const int*   i_idx    = (const int*)d_in[3];
  float* out = (float*)d_out;

  char* w = (char*)d_ws;
  size_t off = 0;
  auto alloc = [&](size_t bytes) -> void* {
    void* p = (void*)(w + off);
    off += (bytes + 255) & ~(size_t)255;
    return p;
  };
  int* cnt_u   = (int*)alloc((size_t)U_NUM * 4);
  int* cnt_i   = (int*)alloc((size_t)I_NUM * 4);
  int* offs_u  = (int*)alloc((size_t)(U_NUM + 1) * 4);
  int* offs_i  = (int*)alloc((size_t)(I_NUM + 1) * 4);
  int* cm_u    = (int*)alloc((size_t)NBLK_E * NBU_U * 4);
  int* cm_i    = (int*)alloc((size_t)NBLK_E * NBU_I * 4);
  int* bm_u    = (int*)alloc((size_t)NBLK_E * NBU_U * 4);
  int* bm_i    = (int*)alloc((size_t)NBLK_E * NBU_I * 4);
  int* tot_u   = (int*)alloc((size_t)NBU_U * 4);
  int* tot_i   = (int*)alloc((size_t)NBU_I * 4);
  int* boffs_u = (int*)alloc((size_t)(NBU_U + 1) * 4);
  int* boffs_i = (int*)alloc((size_t)(NBU_I + 1) * 4);
  int* scr_u   = (int*)alloc((size_t)NBU_U * 4);     // small_scan cur scratch
  int* scr_i   = (int*)alloc((size_t)NBU_I * 4);
  int* dhist_u = (int*)alloc((size_t)DBINS * 4);
  int* dhist_i = (int*)alloc((size_t)DBINS * 4);
  int* doffs_u = (int*)alloc((size_t)(DBINS + 1) * 4);
  int* doffs_i = (int*)alloc((size_t)(DBINS + 1) * 4);
  int* dcur_u  = (int*)alloc((size_t)DBINS * 4);
  int* dcur_i  = (int*)alloc((size_t)DBINS * 4);
  int4* rd_u   = (int4*)alloc((size_t)U_NUM * 16);   // {beg,end,row,0} desc-degree
  int4* rd_i   = (int4*)alloc((size_t)I_NUM * 16);
  int* adj_u   = (int*)alloc((size_t)NE * 4);
  int* adj_i   = (int*)alloc((size_t)NE * 4);
  float* du_inv  = (float*)alloc((size_t)U_NUM * 4);
  float* du_invs = (float*)alloc((size_t)U_NUM * 4);
  float* di_inv  = (float*)alloc((size_t)I_NUM * 4);
  float* di_invs = (float*)alloc((size_t)I_NUM * 4);
  // half-table region, 38.4 MB; the packed bins (16 MB) alias its start and
  // are dead before init_k writes the half tables.
  __half* hreg = (__half*)alloc((size_t)(U_NUM + I_NUM) * 2 * EMB * 2);
  __half* ue_h    = hreg;                                  // U_NUM*64
  __half* ie_h    = ue_h    + (size_t)U_NUM * EMB;         // I_NUM*64
  __half* tmp_i_h = ie_h    + (size_t)I_NUM * EMB;         // I_NUM*64
  __half* tmp_u_h = tmp_i_h + (size_t)I_NUM * EMB;         // U_NUM*64
  int* bin_u = (int*)hreg;            // NE ints (8 MB)
  int* bin_i = bin_u + NE;            // NE ints (8 MB)

  // ---- CSR build (count-matrix radix sort) ----
  hist_k<<<NBLK_E, 256, 0, stream>>>(u_idx, i_idx, cm_u, cm_i, dhist_u, dhist_i);
  colsum_k<<<NBU_T, 256, 0, stream>>>(cm_u, cm_i, tot_u, tot_i);
  small_scan2_k<<<2, 1024, 0, stream>>>(tot_u, boffs_u, scr_u, NBU_U,
                                        tot_i, boffs_i, scr_i, NBU_I);
  colscan_k<<<NBU_T, 256, 0, stream>>>(cm_u, cm_i, boffs_u, boffs_i, bm_u, bm_i);
  binfill_k<<<NBLK_E, 256, 0, stream>>>(u_idx, i_idx, bm_u, bm_i, bin_u, bin_i);
  bucket_build_k<<<NBU_T, 256, 0, stream>>>(bin_u, bin_i, boffs_u, boffs_i,
                                            cnt_u, cnt_i, offs_u, offs_i,
                                            du_inv, du_invs, di_inv, di_invs,
                                            adj_u, adj_i, dhist_u, dhist_i);

  // ---- degree sort (descending rowdesc) ----
  small_scan2_k<<<2, 1024, 0, stream>>>(dhist_u, doffs_u, dcur_u, DBINS,
                                        dhist_i, doffs_i, dcur_i, DBINS);
  deg_scatter_k<<<ceil_div(U_NUM, 2048), 256, 0, stream>>>(cnt_u, offs_u, dcur_u, rd_u, U_NUM);
  deg_scatter_k<<<ceil_div(I_NUM, 2048), 256, 0, stream>>>(cnt_i, offs_i, dcur_i, rd_i, I_NUM);

  // ---- propagation (fp16 tables, fp32 accumulation) ----
  init_k<<<ceil_div((U_NUM + I_NUM) * EMB / 4, 256), 256, 0, stream>>>(
      user_emb, item_emb, du_invs, di_invs, out, ue_h, ie_h);

  float* sum_u = out;
  float* sum_i = out + (size_t)U_NUM * EMB;
  const int pair_grid = ceil_div((U_NUM + I_NUM) * 8, 256);
  for (int l = 0; l < NLAYERS; ++l){
    // A: tmp_i_h = half(d_i_inv * R^T ue_h)   +   C: tmp_u_h = half(d_u_inv * R ie_h)
    spmm_pair<false><<<pair_grid, 256, 0, stream>>>(
        rd_i, adj_i, ue_h, nullptr, di_inv, tmp_i_h, nullptr, I_NUM,
        rd_u, adj_u, ie_h, nullptr, du_inv, tmp_u_h, nullptr, U_NUM);
    // B: sum_u += 0.25*du_invs * R tmp_i_h ; ue_h = half(du_inv * R tmp_i_h)
    // D: sum_i += 0.25*di_invs * R^T tmp_u_h ; ie_h = half(di_inv * R^T tmp_u_h)
    spmm_pair<true><<<pair_grid, 256, 0, stream>>>(
        rd_u, adj_u, tmp_i_h, du_invs, du_inv, ue_h, sum_u, U_NUM,
        rd_i, adj_i, tmp_u_h, di_invs, di_inv, ie_h, sum_i, I_NUM);
  }
}

// Round 5
// 608.439 us; speedup vs baseline: 1.0808x; 1.0084x over previous
//
#include <hip/hip_runtime.h>
#include <hip/hip_fp16.h>
#include <math.h>

#define U_NUM 100000
#define I_NUM 50000
#define NE    2000000
#define EMB   64
#define NLAYERS 3

// bucketing: 512 rows per bucket
#define BSH   9
#define BROWS 512
#define NBU_U ((U_NUM + 511) >> 9)   // 196
#define NBU_I ((I_NUM + 511) >> 9)   // 98
#define NBU_T (NBU_U + NBU_I)        // 294
#define CHUNK 8192
#define NBLK_E ((NE + CHUNK - 1) / CHUNK)   // 245  (must stay <= 256 for colscan_k)
#define DBINS 512
#define PACK_SH 17
#define PACK_MASK 0x1FFFF

static inline int ceil_div(int a, int b){ return (a + b - 1) / b; }

// ---------------- phase 1: per-block bucket counts ----------------
// block 0/1 also zero the degree histograms (saves two memset launches)

__global__ void hist_k(const int* __restrict__ u_idx, const int* __restrict__ i_idx,
                       int* __restrict__ cm_u, int* __restrict__ cm_i,
                       int* __restrict__ dhist_u, int* __restrict__ dhist_i){
  if (blockIdx.x == 0){
    for (int t = threadIdx.x; t < DBINS; t += 256) dhist_u[t] = 0;
  } else if (blockIdx.x == 1){
    for (int t = threadIdx.x; t < DBINS; t += 256) dhist_i[t] = 0;
  }
  __shared__ int h[NBU_T];
  for (int t = threadIdx.x; t < NBU_T; t += 256) h[t] = 0;
  __syncthreads();
  int base = blockIdx.x * CHUNK;
  int end = min(base + CHUNK, NE);
  for (int e = base + (threadIdx.x << 1); e < end; e += 512){
    int2 uu = *(const int2*)(u_idx + e);
    int2 ii = *(const int2*)(i_idx + e);
    atomicAdd(&h[uu.x >> BSH], 1);
    atomicAdd(&h[uu.y >> BSH], 1);
    atomicAdd(&h[NBU_U + (ii.x >> BSH)], 1);
    atomicAdd(&h[NBU_U + (ii.y >> BSH)], 1);
  }
  __syncthreads();
  for (int t = threadIdx.x; t < NBU_U; t += 256) cm_u[blockIdx.x * NBU_U + t] = h[t];
  for (int t = threadIdx.x; t < NBU_I; t += 256) cm_i[blockIdx.x * NBU_I + t] = h[NBU_U + t];
}

// column sums of the count matrices -> per-bucket totals
__global__ void colsum_k(const int* __restrict__ cm_u, const int* __restrict__ cm_i,
                         int* __restrict__ tot_u, int* __restrict__ tot_i){
  __shared__ int s[256];
  int j = blockIdx.x;
  const int* cm; int* tot; int jj, stride;
  if (j < NBU_U){ cm = cm_u; tot = tot_u; jj = j; stride = NBU_U; }
  else { cm = cm_i; tot = tot_i; jj = j - NBU_U; stride = NBU_I; }
  int acc = 0;
  for (int b = threadIdx.x; b < NBLK_E; b += 256) acc += cm[b * stride + jj];
  s[threadIdx.x] = acc; __syncthreads();
  for (int o = 128; o > 0; o >>= 1){
    if (threadIdx.x < o) s[threadIdx.x] += s[threadIdx.x + o];
    __syncthreads();
  }
  if (threadIdx.x == 0) tot[jj] = s[0];
}

// paired single-block exclusive scans (block 0 -> set A, block 1 -> set B)
__global__ void small_scan2_k(const int* __restrict__ cA, int* __restrict__ oA,
                              int* __restrict__ rA, int nA,
                              const int* __restrict__ cB, int* __restrict__ oB,
                              int* __restrict__ rB, int nB){
  const int* cnt; int* offs; int* cur; int n;
  if (blockIdx.x == 0){ cnt = cA; offs = oA; cur = rA; n = nA; }
  else { cnt = cB; offs = oB; cur = rB; n = nB; }
  __shared__ int s[1024];
  int t = threadIdx.x;
  int v = (t < n) ? cnt[t] : 0;
  s[t] = v; __syncthreads();
  for (int o = 1; o < 1024; o <<= 1){
    int x = (t >= o) ? s[t - o] : 0;
    __syncthreads();
    s[t] += x;
    __syncthreads();
  }
  int excl = (t > 0) ? s[t - 1] : 0;
  if (t < n){ offs[t] = excl; cur[t] = excl; }
  if (t == n - 1) offs[n] = s[t];
}

// per-bucket column scan: basemat[b][j] = boffs[j] + sum_{b'<b} cm[b'][j]
__global__ void colscan_k(const int* __restrict__ cm_u, const int* __restrict__ cm_i,
                          const int* __restrict__ boffs_u, const int* __restrict__ boffs_i,
                          int* __restrict__ bm_u, int* __restrict__ bm_i){
  __shared__ int s[256];
  int j = blockIdx.x;
  const int* cm; const int* boffs; int* bm; int jj, stride;
  if (j < NBU_U){ cm = cm_u; boffs = boffs_u; bm = bm_u; jj = j; stride = NBU_U; }
  else { cm = cm_i; boffs = boffs_i; bm = bm_i; jj = j - NBU_U; stride = NBU_I; }
  int t = threadIdx.x;
  int v = (t < NBLK_E) ? cm[t * stride + jj] : 0;
  s[t] = v; __syncthreads();
  for (int o = 1; o < 256; o <<= 1){
    int x = (t >= o) ? s[t - o] : 0;
    __syncthreads();
    s[t] += x;
    __syncthreads();
  }
  int excl = (t > 0) ? s[t - 1] : 0;
  if (t < NBLK_E) bm[t * stride + jj] = excl + boffs[jj];
}

// ---------------- phase 2: scatter edges into bucket-sorted bins ----------------
// packed bin entry: (row_local << 17) | neighbor  (row_local < 512, neighbor < 2^17)

__global__ void binfill_k(const int* __restrict__ u_idx, const int* __restrict__ i_idx,
                          const int* __restrict__ bm_u, const int* __restrict__ bm_i,
                          int* __restrict__ bin_u, int* __restrict__ bin_i){
  __shared__ int cur[NBU_T];
  for (int t = threadIdx.x; t < NBU_U; t += 256) cur[t] = bm_u[blockIdx.x * NBU_U + t];
  for (int t = threadIdx.x; t < NBU_I; t += 256) cur[NBU_U + t] = bm_i[blockIdx.x * NBU_I + t];
  __syncthreads();
  int base = blockIdx.x * CHUNK;
  int end = min(base + CHUNK, NE);
  for (int e = base + (threadIdx.x << 1); e < end; e += 512){
    int2 uu = *(const int2*)(u_idx + e);
    int2 ii = *(const int2*)(i_idx + e);
    int p;
    p = atomicAdd(&cur[uu.x >> BSH], 1);            bin_u[p] = ((uu.x & 511) << PACK_SH) | ii.x;
    p = atomicAdd(&cur[uu.y >> BSH], 1);            bin_u[p] = ((uu.y & 511) << PACK_SH) | ii.y;
    p = atomicAdd(&cur[NBU_U + (ii.x >> BSH)], 1);  bin_i[p] = ((ii.x & 511) << PACK_SH) | uu.x;
    p = atomicAdd(&cur[NBU_U + (ii.y >> BSH)], 1);  bin_i[p] = ((ii.y & 511) << PACK_SH) | uu.y;
  }
}

// ---------------- phase 3: per-bucket CSR build (cnt/offs/norms/adj + LDS deg hist) ----------------

__global__ void bucket_build_k(const int* __restrict__ bin_u, const int* __restrict__ bin_i,
                               const int* __restrict__ boffs_u, const int* __restrict__ boffs_i,
                               int* __restrict__ cnt_u, int* __restrict__ cnt_i,
                               int* __restrict__ offs_u, int* __restrict__ offs_i,
                               float* __restrict__ du_inv, float* __restrict__ du_invs,
                               float* __restrict__ di_inv, float* __restrict__ di_invs,
                               int* __restrict__ adj_u, int* __restrict__ adj_i,
                               int* __restrict__ dhist_u, int* __restrict__ dhist_i){
  __shared__ int h[BROWS];
  __shared__ int part[256];
  __shared__ int dh[DBINS];
  int b = blockIdx.x;
  const int* bin; const int* boffs; int* cnt; int* offs; float* inv; float* invs;
  int* adj; int* dhist; int jj, nrows;
  if (b < NBU_U){
    bin = bin_u; boffs = boffs_u; cnt = cnt_u; offs = offs_u;
    inv = du_inv; invs = du_invs; adj = adj_u; dhist = dhist_u; jj = b; nrows = U_NUM;
  } else {
    bin = bin_i; boffs = boffs_i; cnt = cnt_i; offs = offs_i;
    inv = di_inv; invs = di_invs; adj = adj_i; dhist = dhist_i; jj = b - NBU_U; nrows = I_NUM;
  }
  int tid = threadIdx.x;
  int r0 = jj << BSH;
  int beg = boffs[jj], end = boffs[jj + 1];
  h[2*tid] = 0; h[2*tid + 1] = 0;
  for (int t = tid; t < DBINS; t += 256) dh[t] = 0;
  __syncthreads();
  for (int e = beg + tid; e < end; e += 256)
    atomicAdd(&h[((unsigned)bin[e]) >> PACK_SH], 1);
  __syncthreads();
  int c0 = h[2*tid], c1 = h[2*tid + 1];
  part[tid] = c0 + c1; __syncthreads();
  for (int o = 1; o < 256; o <<= 1){
    int x = (tid >= o) ? part[tid - o] : 0;
    __syncthreads();
    part[tid] += x;
    __syncthreads();
  }
  int excl = (tid > 0) ? part[tid - 1] : 0;
  h[2*tid] = excl;
  h[2*tid + 1] = excl + c0;
#pragma unroll
  for (int k = 0; k < 2; ++k){
    int l = 2*tid + k;
    int row = r0 + l;
    int c = k ? c1 : c0;
    int o = k ? (excl + c0) : excl;
    if (row < nrows){
      cnt[row] = c;
      offs[row] = beg + o;
      float d = (c > 0) ? (float)c : 1.0f;
      inv[row]  = 1.0f / d;
      invs[row] = 1.0f / sqrtf(d);
      atomicAdd(&dh[min(c, DBINS - 1)], 1);
    } else if (row == nrows){
      offs[row] = beg + o;   // global sentinel (== NE in the last bucket)
    }
  }
  __syncthreads();
  // scatter adj using h as cursors (bucket-local CSR layout)
  for (int e = beg + tid; e < end; e += 256){
    int v = bin[e];
    int slot = beg + atomicAdd(&h[((unsigned)v) >> PACK_SH], 1);
    adj[slot] = v & PACK_MASK;
  }
  __syncthreads();
  for (int t = tid; t < DBINS; t += 256) if (dh[t]) atomicAdd(&dhist[t], dh[t]);
}

// ---------------- degree sort (counting sort -> DESCENDING row descriptors) ----------------
// rd[rid] = {beg, end, row, 0}: one 16-B load in the SpMM replaces the
// perm[rid] -> offs[row] dependent-load chain (removes one serial latency).

__global__ void deg_scatter_k(const int* __restrict__ cnt, const int* __restrict__ offs,
                              int* __restrict__ dcur, int4* __restrict__ rd, int n){
  __shared__ int h[DBINS];
  __shared__ int base_s[DBINS];
  for (int t = threadIdx.x; t < DBINS; t += 256) h[t] = 0;
  __syncthreads();
  int base = blockIdx.x * 2048;
  int end = min(base + 2048, n);
  for (int r = base + threadIdx.x; r < end; r += 256)
    atomicAdd(&h[min(cnt[r], DBINS - 1)], 1);
  __syncthreads();
  for (int t = threadIdx.x; t < DBINS; t += 256){
    int c = h[t];
    base_s[t] = c ? atomicAdd(&dcur[t], c) : 0;
    h[t] = 0;
  }
  __syncthreads();
  for (int r = base + threadIdx.x; r < end; r += 256){
    int c = cnt[r];
    int b = min(c, DBINS - 1);
    int pos = base_s[b] + atomicAdd(&h[b], 1);
    int bg = offs[r];
    rd[n - 1 - pos] = make_int4(bg, bg + c, r, 0);   // descending degree
  }
}

// ---------------- fused init: out = 0.25*emb ; half tables = emb * pre-scale ----------------

__global__ void init_k(const float* __restrict__ ue, const float* __restrict__ ie,
                       const float* __restrict__ dus, const float* __restrict__ dis,
                       float* __restrict__ out, __half* __restrict__ ue_h,
                       __half* __restrict__ ie_h){
  int idx4 = blockIdx.x * blockDim.x + threadIdx.x;   // one float4 per thread
  const int nu4 = U_NUM * (EMB / 4);
  const int tot4 = (U_NUM + I_NUM) * (EMB / 4);
  if (idx4 >= tot4) return;
  const float* e; __half* hp; float s; int loc;
  if (idx4 < nu4){ e = ue; hp = ue_h; loc = idx4; s = dus[idx4 >> 4]; }
  else { e = ie; hp = ie_h; loc = idx4 - nu4; s = dis[(idx4 - nu4) >> 4]; }
  float4 v = ((const float4*)e)[loc];
  float4 o = make_float4(v.x * 0.25f, v.y * 0.25f, v.z * 0.25f, v.w * 0.25f);
  ((float4*)out)[idx4] = o;
  __half2 h01 = __floats2half2_rn(v.x * s, v.y * s);
  __half2 h23 = __floats2half2_rn(v.z * s, v.w * s);
  ((__half2*)hp)[loc * 2]     = h01;
  ((__half2*)hp)[loc * 2 + 1] = h23;
}

// ---------------- fp16 gather SpMM, paired (two independent SpMMs per launch) ----------------
// 8 lanes per row, each lane owns 8 halves (16 B) -> one float4 gather per edge
// per lane. adj batch prefetch via shuffle-broadcast: lane l of the 8-lane
// row-group holds adj[j + 8g + l] (ONE int), next batch's load issues before
// the current gathers' wait, and indices are redistributed with __shfl(w=8)
// at use time. Removes the serial adj-load wait from every iteration at a
// cost of ~1 VGPR (R3's 8-deep manual rotation cost 8 VGPRs and lost).
// rd is degree-DESCENDING. Epilogue: dst_h[row] = half(acc * post_h[row]);
// if HAS_SUM: sum[row] += acc * post_sum[row] * 0.25.

__device__ __forceinline__ void acc8(float* a, float4 v){
  union { float4 f; __half2 h[4]; } u;
  u.f = v;
#pragma unroll
  for (int k = 0; k < 4; ++k){
    float2 f = __half22float2(u.h[k]);
    a[2*k]     += f.x;
    a[2*k + 1] += f.y;
  }
}

template<bool HAS_SUM>
__global__ void spmm_pair(
    const int4* __restrict__ rdA, const int* __restrict__ adjA,
    const __half* __restrict__ srcA, const float* __restrict__ psA, const float* __restrict__ phA,
    __half* __restrict__ dstA, float* __restrict__ sumA, int nA,
    const int4* __restrict__ rdB, const int* __restrict__ adjB,
    const __half* __restrict__ srcB, const float* __restrict__ psB, const float* __restrict__ phB,
    __half* __restrict__ dstB, float* __restrict__ sumB, int nB){
  int t = blockIdx.x * blockDim.x + threadIdx.x;
  int rid = t >> 3;
  int lane = t & 7;
  const int4* rd; const int* adj; const __half* src; const float* ps; const float* ph;
  __half* dst; float* sum;
  if (rid < nA){
    rd = rdA; adj = adjA; src = srcA; ps = psA; ph = phA; dst = dstA; sum = sumA;
  } else {
    rid -= nA;
    if (rid >= nB) return;
    rd = rdB; adj = adjB; src = srcB; ps = psB; ph = phB; dst = dstB; sum = sumB;
  }
  int4 d = rd[rid];
  int beg = d.x, end = d.y, row = d.z;
  const __half* sp8 = src + (size_t)(lane << 3);   // lane's 16 B slice base
  float acc[8];
#pragma unroll
  for (int k = 0; k < 8; ++k) acc[k] = 0.f;

  int nfull = (end - beg) >> 3;
  int j = beg + (nfull << 3);          // tail start
  if (nfull > 0){
    int nx = adj[beg + lane];          // batch 0: one index per lane
    for (int g = 1; g < nfull; ++g){
      int cur = nx;
      nx = adj[beg + (g << 3) + lane]; // prefetch next batch (indep, issues early)
      int n0 = __shfl(cur, 0, 8), n1 = __shfl(cur, 1, 8);
      int n2 = __shfl(cur, 2, 8), n3 = __shfl(cur, 3, 8);
      int n4 = __shfl(cur, 4, 8), n5 = __shfl(cur, 5, 8);
      int n6 = __shfl(cur, 6, 8), n7 = __shfl(cur, 7, 8);
      float4 a0 = *(const float4*)(sp8 + (((size_t)n0) << 6));
      float4 a1 = *(const float4*)(sp8 + (((size_t)n1) << 6));
      float4 a2 = *(const float4*)(sp8 + (((size_t)n2) << 6));
      float4 a3 = *(const float4*)(sp8 + (((size_t)n3) << 6));
      float4 a4 = *(const float4*)(sp8 + (((size_t)n4) << 6));
      float4 a5 = *(const float4*)(sp8 + (((size_t)n5) << 6));
      float4 a6 = *(const float4*)(sp8 + (((size_t)n6) << 6));
      float4 a7 = *(const float4*)(sp8 + (((size_t)n7) << 6));
      acc8(acc, a0); acc8(acc, a1); acc8(acc, a2); acc8(acc, a3);
      acc8(acc, a4); acc8(acc, a5); acc8(acc, a6); acc8(acc, a7);
    }
    int cur = nx;                      // last full batch
    int n0 = __shfl(cur, 0, 8), n1 = __shfl(cur, 1, 8);
    int n2 = __shfl(cur, 2, 8), n3 = __shfl(cur, 3, 8);
    int n4 = __shfl(cur, 4, 8), n5 = __shfl(cur, 5, 8);
    int n6 = __shfl(cur, 6, 8), n7 = __shfl(cur, 7, 8);
    float4 a0 = *(const float4*)(sp8 + (((size_t)n0) << 6));
    float4 a1 = *(const float4*)(sp8 + (((size_t)n1) << 6));
    float4 a2 = *(const float4*)(sp8 + (((size_t)n2) << 6));
    float4 a3 = *(const float4*)(sp8 + (((size_t)n3) << 6));
    float4 a4 = *(const float4*)(sp8 + (((size_t)n4) << 6));
    float4 a5 = *(const float4*)(sp8 + (((size_t)n5) << 6));
    float4 a6 = *(const float4*)(sp8 + (((size_t)n6) << 6));
    float4 a7 = *(const float4*)(sp8 + (((size_t)n7) << 6));
    acc8(acc, a0); acc8(acc, a1); acc8(acc, a2); acc8(acc, a3);
    acc8(acc, a4); acc8(acc, a5); acc8(acc, a6); acc8(acc, a7);
  }
  for (; j < end; ++j){
    int n0 = adj[j];
    float4 a0 = *(const float4*)(sp8 + (((size_t)n0) << 6));
    acc8(acc, a0);
  }
  float phv = ph[row];
  union { float4 f; __half2 h[4]; } ob;
#pragma unroll
  for (int k = 0; k < 4; ++k)
    ob.h[k] = __floats2half2_rn(acc[2*k] * phv, acc[2*k + 1] * phv);
  *(float4*)(dst + (((size_t)row) << 6) + (size_t)(lane << 3)) = ob.f;
  if (HAS_SUM){
    float psv = ps[row] * 0.25f;
    float4* sp = (float4*)(sum + (((size_t)row) << 6) + (size_t)(lane << 3));
#pragma unroll
    for (int k = 0; k < 2; ++k){
      float4 s = sp[k];
      s.x += acc[4*k]     * psv;
      s.y += acc[4*k + 1] * psv;
      s.z += acc[4*k + 2] * psv;
      s.w += acc[4*k + 3] * psv;
      sp[k] = s;
    }
  }
}

// ---------------- driver ----------------

extern "C" void kernel_launch(void* const* d_in, const int* in_sizes, int n_in,
                              void* d_out, int out_size, void* d_ws, size_t ws_size,
                              hipStream_t stream){
  const float* user_emb = (const float*)d_in[0];
  const float* item_emb = (const float*)d_in[1];
  const int*   u_idx    = (const int*)d_in[2];
  const int*   i_idx    = (const int*)d_in[3];
  float* out = (float*)d_out;

  char* w = (char*)d_ws;
  size_t off = 0;
  auto alloc = [&](size_t bytes) -> void* {
    void* p = (void*)(w + off);
    off += (bytes + 255) & ~(size_t)255;
    return p;
  };
  int* cnt_u   = (int*)alloc((size_t)U_NUM * 4);
  int* cnt_i   = (int*)alloc((size_t)I_NUM * 4);
  int* offs_u  = (int*)alloc((size_t)(U_NUM + 1) * 4);
  int* offs_i  = (int*)alloc((size_t)(I_NUM + 1) * 4);
  int* cm_u    = (int*)alloc((size_t)NBLK_E * NBU_U * 4);
  int* cm_i    = (int*)alloc((size_t)NBLK_E * NBU_I * 4);
  int* bm_u    = (int*)alloc((size_t)NBLK_E * NBU_U * 4);
  int* bm_i    = (int*)alloc((size_t)NBLK_E * NBU_I * 4);
  int* tot_u   = (int*)alloc((size_t)NBU_U * 4);
  int* tot_i   = (int*)alloc((size_t)NBU_I * 4);
  int* boffs_u = (int*)alloc((size_t)(NBU_U + 1) * 4);
  int* boffs_i = (int*)alloc((size_t)(NBU_I + 1) * 4);
  int* scr_u   = (int*)alloc((size_t)NBU_U * 4);     // small_scan cur scratch
  int* scr_i   = (int*)alloc((size_t)NBU_I * 4);
  int* dhist_u = (int*)alloc((size_t)DBINS * 4);
  int* dhist_i = (int*)alloc((size_t)DBINS * 4);
  int* doffs_u = (int*)alloc((size_t)(DBINS + 1) * 4);
  int* doffs_i = (int*)alloc((size_t)(DBINS + 1) * 4);
  int* dcur_u  = (int*)alloc((size_t)DBINS * 4);
  int* dcur_i  = (int*)alloc((size_t)DBINS * 4);
  int4* rd_u   = (int4*)alloc((size_t)U_NUM * 16);   // {beg,end,row,0} desc-degree
  int4* rd_i   = (int4*)alloc((size_t)I_NUM * 16);
  int* adj_u   = (int*)alloc((size_t)NE * 4);
  int* adj_i   = (int*)alloc((size_t)NE * 4);
  float* du_inv  = (float*)alloc((size_t)U_NUM * 4);
  float* du_invs = (float*)alloc((size_t)U_NUM * 4);
  float* di_inv  = (float*)alloc((size_t)I_NUM * 4);
  float* di_invs = (float*)alloc((size_t)I_NUM * 4);
  // half-table region, 38.4 MB; the packed bins (16 MB) alias its start and
  // are dead before init_k writes the half tables.
  __half* hreg = (__half*)alloc((size_t)(U_NUM + I_NUM) * 2 * EMB * 2);
  __half* ue_h    = hreg;                                  // U_NUM*64
  __half* ie_h    = ue_h    + (size_t)U_NUM * EMB;         // I_NUM*64
  __half* tmp_i_h = ie_h    + (size_t)I_NUM * EMB;         // I_NUM*64
  __half* tmp_u_h = tmp_i_h + (size_t)I_NUM * EMB;         // U_NUM*64
  int* bin_u = (int*)hreg;            // NE ints (8 MB)
  int* bin_i = bin_u + NE;            // NE ints (8 MB)

  // ---- CSR build (count-matrix radix sort) ----
  hist_k<<<NBLK_E, 256, 0, stream>>>(u_idx, i_idx, cm_u, cm_i, dhist_u, dhist_i);
  colsum_k<<<NBU_T, 256, 0, stream>>>(cm_u, cm_i, tot_u, tot_i);
  small_scan2_k<<<2, 1024, 0, stream>>>(tot_u, boffs_u, scr_u, NBU_U,
                                        tot_i, boffs_i, scr_i, NBU_I);
  colscan_k<<<NBU_T, 256, 0, stream>>>(cm_u, cm_i, boffs_u, boffs_i, bm_u, bm_i);
  binfill_k<<<NBLK_E, 256, 0, stream>>>(u_idx, i_idx, bm_u, bm_i, bin_u, bin_i);
  bucket_build_k<<<NBU_T, 256, 0, stream>>>(bin_u, bin_i, boffs_u, boffs_i,
                                            cnt_u, cnt_i, offs_u, offs_i,
                                            du_inv, du_invs, di_inv, di_invs,
                                            adj_u, adj_i, dhist_u, dhist_i);

  // ---- degree sort (descending rowdesc) ----
  small_scan2_k<<<2, 1024, 0, stream>>>(dhist_u, doffs_u, dcur_u, DBINS,
                                        dhist_i, doffs_i, dcur_i, DBINS);
  deg_scatter_k<<<ceil_div(U_NUM, 2048), 256, 0, stream>>>(cnt_u, offs_u, dcur_u, rd_u, U_NUM);
  deg_scatter_k<<<ceil_div(I_NUM, 2048), 256, 0, stream>>>(cnt_i, offs_i, dcur_i, rd_i, I_NUM);

  // ---- propagation (fp16 tables, fp32 accumulation) ----
  init_k<<<ceil_div((U_NUM + I_NUM) * EMB / 4, 256), 256, 0, stream>>>(
      user_emb, item_emb, du_invs, di_invs, out, ue_h, ie_h);

  float* sum_u = out;
  float* sum_i = out + (size_t)U_NUM * EMB;
  const int pair_grid = ceil_div((U_NUM + I_NUM) * 8, 256);
  for (int l = 0; l < NLAYERS; ++l){
    // A: tmp_i_h = half(d_i_inv * R^T ue_h)   +   C: tmp_u_h = half(d_u_inv * R ie_h)
    spmm_pair<false><<<pair_grid, 256, 0, stream>>>(
        rd_i, adj_i, ue_h, nullptr, di_inv, tmp_i_h, nullptr, I_NUM,
        rd_u, adj_u, ie_h, nullptr, du_inv, tmp_u_h, nullptr, U_NUM);
    // B: sum_u += 0.25*du_invs * R tmp_i_h ; ue_h = half(du_inv * R tmp_i_h)
    // D: sum_i += 0.25*di_invs * R^T tmp_u_h ; ie_h = half(di_inv * R^T tmp_u_h)
    spmm_pair<true><<<pair_grid, 256, 0, stream>>>(
        rd_u, adj_u, tmp_i_h, du_invs, du_inv, ue_h, sum_u, U_NUM,
        rd_i, adj_i, tmp_u_h, di_invs, di_inv, ie_h, sum_i, I_NUM);
  }
}

// Round 6
// 515.366 us; speedup vs baseline: 1.2760x; 1.1806x over previous
//
#include <hip/hip_runtime.h>
#include <hip/hip_fp16.h>
#include <math.h>

#define U_NUM 100000
#define I_NUM 50000
#define NE    2000000
#define EMB   64
#define NLAYERS 3

// bucketing: 512 rows per bucket
#define BSH   9
#define BROWS 512
#define NBU_U ((U_NUM + 511) >> 9)   // 196
#define NBU_I ((I_NUM + 511) >> 9)   // 98
#define NBU_T (NBU_U + NBU_I)        // 294
#define CHUNK 8192
#define NBLK_E ((NE + CHUNK - 1) / CHUNK)   // 245  (must stay <= 256 for colscan_k)
#define DBINS 512
#define PACK_SH 17
#define PACK_MASK 0x1FFFF

// fp8 table scale: values ~1e-3..1e-2 are below e4m3's sweet range; S lifts
// them to ~0.5..8. S propagates through the SpMM chain transparently (each
// dst = ph * sum(src) keeps the factor); only init (*S) and the fp32 sum
// epilogue (0.25/S) touch it. Worst-case same-sign row sum ~270 < 448 max.
#define FP8_SCALE 512.0f

typedef float v2f __attribute__((ext_vector_type(2)));

static inline int ceil_div(int a, int b){ return (a + b - 1) / b; }

// ---------------- phase 1: per-block bucket counts ----------------
// block 0/1 also zero the degree histograms (saves two memset launches)

__global__ void hist_k(const int* __restrict__ u_idx, const int* __restrict__ i_idx,
                       int* __restrict__ cm_u, int* __restrict__ cm_i,
                       int* __restrict__ dhist_u, int* __restrict__ dhist_i){
  if (blockIdx.x == 0){
    for (int t = threadIdx.x; t < DBINS; t += 256) dhist_u[t] = 0;
  } else if (blockIdx.x == 1){
    for (int t = threadIdx.x; t < DBINS; t += 256) dhist_i[t] = 0;
  }
  __shared__ int h[NBU_T];
  for (int t = threadIdx.x; t < NBU_T; t += 256) h[t] = 0;
  __syncthreads();
  int base = blockIdx.x * CHUNK;
  int end = min(base + CHUNK, NE);
  for (int e = base + (threadIdx.x << 1); e < end; e += 512){
    int2 uu = *(const int2*)(u_idx + e);
    int2 ii = *(const int2*)(i_idx + e);
    atomicAdd(&h[uu.x >> BSH], 1);
    atomicAdd(&h[uu.y >> BSH], 1);
    atomicAdd(&h[NBU_U + (ii.x >> BSH)], 1);
    atomicAdd(&h[NBU_U + (ii.y >> BSH)], 1);
  }
  __syncthreads();
  for (int t = threadIdx.x; t < NBU_U; t += 256) cm_u[blockIdx.x * NBU_U + t] = h[t];
  for (int t = threadIdx.x; t < NBU_I; t += 256) cm_i[blockIdx.x * NBU_I + t] = h[NBU_U + t];
}

// column sums of the count matrices -> per-bucket totals
__global__ void colsum_k(const int* __restrict__ cm_u, const int* __restrict__ cm_i,
                         int* __restrict__ tot_u, int* __restrict__ tot_i){
  __shared__ int s[256];
  int j = blockIdx.x;
  const int* cm; int* tot; int jj, stride;
  if (j < NBU_U){ cm = cm_u; tot = tot_u; jj = j; stride = NBU_U; }
  else { cm = cm_i; tot = tot_i; jj = j - NBU_U; stride = NBU_I; }
  int acc = 0;
  for (int b = threadIdx.x; b < NBLK_E; b += 256) acc += cm[b * stride + jj];
  s[threadIdx.x] = acc; __syncthreads();
  for (int o = 128; o > 0; o >>= 1){
    if (threadIdx.x < o) s[threadIdx.x] += s[threadIdx.x + o];
    __syncthreads();
  }
  if (threadIdx.x == 0) tot[jj] = s[0];
}

// paired single-block exclusive scans (block 0 -> set A, block 1 -> set B)
__global__ void small_scan2_k(const int* __restrict__ cA, int* __restrict__ oA,
                              int* __restrict__ rA, int nA,
                              const int* __restrict__ cB, int* __restrict__ oB,
                              int* __restrict__ rB, int nB){
  const int* cnt; int* offs; int* cur; int n;
  if (blockIdx.x == 0){ cnt = cA; offs = oA; cur = rA; n = nA; }
  else { cnt = cB; offs = oB; cur = rB; n = nB; }
  __shared__ int s[1024];
  int t = threadIdx.x;
  int v = (t < n) ? cnt[t] : 0;
  s[t] = v; __syncthreads();
  for (int o = 1; o < 1024; o <<= 1){
    int x = (t >= o) ? s[t - o] : 0;
    __syncthreads();
    s[t] += x;
    __syncthreads();
  }
  int excl = (t > 0) ? s[t - 1] : 0;
  if (t < n){ offs[t] = excl; cur[t] = excl; }
  if (t == n - 1) offs[n] = s[t];
}

// per-bucket column scan: basemat[b][j] = boffs[j] + sum_{b'<b} cm[b'][j]
__global__ void colscan_k(const int* __restrict__ cm_u, const int* __restrict__ cm_i,
                          const int* __restrict__ boffs_u, const int* __restrict__ boffs_i,
                          int* __restrict__ bm_u, int* __restrict__ bm_i){
  __shared__ int s[256];
  int j = blockIdx.x;
  const int* cm; const int* boffs; int* bm; int jj, stride;
  if (j < NBU_U){ cm = cm_u; boffs = boffs_u; bm = bm_u; jj = j; stride = NBU_U; }
  else { cm = cm_i; boffs = boffs_i; bm = bm_i; jj = j - NBU_U; stride = NBU_I; }
  int t = threadIdx.x;
  int v = (t < NBLK_E) ? cm[t * stride + jj] : 0;
  s[t] = v; __syncthreads();
  for (int o = 1; o < 256; o <<= 1){
    int x = (t >= o) ? s[t - o] : 0;
    __syncthreads();
    s[t] += x;
    __syncthreads();
  }
  int excl = (t > 0) ? s[t - 1] : 0;
  if (t < NBLK_E) bm[t * stride + jj] = excl + boffs[jj];
}

// ---------------- phase 2: scatter edges into bucket-sorted bins ----------------
// packed bin entry: (row_local << 17) | neighbor  (row_local < 512, neighbor < 2^17)

__global__ void binfill_k(const int* __restrict__ u_idx, const int* __restrict__ i_idx,
                          const int* __restrict__ bm_u, const int* __restrict__ bm_i,
                          int* __restrict__ bin_u, int* __restrict__ bin_i){
  __shared__ int cur[NBU_T];
  for (int t = threadIdx.x; t < NBU_U; t += 256) cur[t] = bm_u[blockIdx.x * NBU_U + t];
  for (int t = threadIdx.x; t < NBU_I; t += 256) cur[NBU_U + t] = bm_i[blockIdx.x * NBU_I + t];
  __syncthreads();
  int base = blockIdx.x * CHUNK;
  int end = min(base + CHUNK, NE);
  for (int e = base + (threadIdx.x << 1); e < end; e += 512){
    int2 uu = *(const int2*)(u_idx + e);
    int2 ii = *(const int2*)(i_idx + e);
    int p;
    p = atomicAdd(&cur[uu.x >> BSH], 1);            bin_u[p] = ((uu.x & 511) << PACK_SH) | ii.x;
    p = atomicAdd(&cur[uu.y >> BSH], 1);            bin_u[p] = ((uu.y & 511) << PACK_SH) | ii.y;
    p = atomicAdd(&cur[NBU_U + (ii.x >> BSH)], 1);  bin_i[p] = ((ii.x & 511) << PACK_SH) | uu.x;
    p = atomicAdd(&cur[NBU_U + (ii.y >> BSH)], 1);  bin_i[p] = ((ii.y & 511) << PACK_SH) | uu.y;
  }
}

// ---------------- phase 3: per-bucket CSR build (cnt/offs/norms/adj + LDS deg hist) ----------------

__global__ void bucket_build_k(const int* __restrict__ bin_u, const int* __restrict__ bin_i,
                               const int* __restrict__ boffs_u, const int* __restrict__ boffs_i,
                               int* __restrict__ cnt_u, int* __restrict__ cnt_i,
                               int* __restrict__ offs_u, int* __restrict__ offs_i,
                               float* __restrict__ du_inv, float* __restrict__ du_invs,
                               float* __restrict__ di_inv, float* __restrict__ di_invs,
                               int* __restrict__ adj_u, int* __restrict__ adj_i,
                               int* __restrict__ dhist_u, int* __restrict__ dhist_i){
  __shared__ int h[BROWS];
  __shared__ int part[256];
  __shared__ int dh[DBINS];
  int b = blockIdx.x;
  const int* bin; const int* boffs; int* cnt; int* offs; float* inv; float* invs;
  int* adj; int* dhist; int jj, nrows;
  if (b < NBU_U){
    bin = bin_u; boffs = boffs_u; cnt = cnt_u; offs = offs_u;
    inv = du_inv; invs = du_invs; adj = adj_u; dhist = dhist_u; jj = b; nrows = U_NUM;
  } else {
    bin = bin_i; boffs = boffs_i; cnt = cnt_i; offs = offs_i;
    inv = di_inv; invs = di_invs; adj = adj_i; dhist = dhist_i; jj = b - NBU_U; nrows = I_NUM;
  }
  int tid = threadIdx.x;
  int r0 = jj << BSH;
  int beg = boffs[jj], end = boffs[jj + 1];
  h[2*tid] = 0; h[2*tid + 1] = 0;
  for (int t = tid; t < DBINS; t += 256) dh[t] = 0;
  __syncthreads();
  for (int e = beg + tid; e < end; e += 256)
    atomicAdd(&h[((unsigned)bin[e]) >> PACK_SH], 1);
  __syncthreads();
  int c0 = h[2*tid], c1 = h[2*tid + 1];
  part[tid] = c0 + c1; __syncthreads();
  for (int o = 1; o < 256; o <<= 1){
    int x = (tid >= o) ? part[tid - o] : 0;
    __syncthreads();
    part[tid] += x;
    __syncthreads();
  }
  int excl = (tid > 0) ? part[tid - 1] : 0;
  h[2*tid] = excl;
  h[2*tid + 1] = excl + c0;
#pragma unroll
  for (int k = 0; k < 2; ++k){
    int l = 2*tid + k;
    int row = r0 + l;
    int c = k ? c1 : c0;
    int o = k ? (excl + c0) : excl;
    if (row < nrows){
      cnt[row] = c;
      offs[row] = beg + o;
      float d = (c > 0) ? (float)c : 1.0f;
      inv[row]  = 1.0f / d;
      invs[row] = 1.0f / sqrtf(d);
      atomicAdd(&dh[min(c, DBINS - 1)], 1);
    } else if (row == nrows){
      offs[row] = beg + o;   // global sentinel (== NE in the last bucket)
    }
  }
  __syncthreads();
  // scatter adj using h as cursors (bucket-local CSR layout)
  for (int e = beg + tid; e < end; e += 256){
    int v = bin[e];
    int slot = beg + atomicAdd(&h[((unsigned)v) >> PACK_SH], 1);
    adj[slot] = v & PACK_MASK;
  }
  __syncthreads();
  for (int t = tid; t < DBINS; t += 256) if (dh[t]) atomicAdd(&dhist[t], dh[t]);
}

// ---------------- degree sort (counting sort -> DESCENDING row descriptors) ----------------
// rd[rid] = {beg, end, row, 0}: one 16-B load in the SpMM replaces the
// perm[rid] -> offs[row] dependent-load chain.

__global__ void deg_scatter_k(const int* __restrict__ cnt, const int* __restrict__ offs,
                              int* __restrict__ dcur, int4* __restrict__ rd, int n){
  __shared__ int h[DBINS];
  __shared__ int base_s[DBINS];
  for (int t = threadIdx.x; t < DBINS; t += 256) h[t] = 0;
  __syncthreads();
  int base = blockIdx.x * 2048;
  int end = min(base + 2048, n);
  for (int r = base + threadIdx.x; r < end; r += 256)
    atomicAdd(&h[min(cnt[r], DBINS - 1)], 1);
  __syncthreads();
  for (int t = threadIdx.x; t < DBINS; t += 256){
    int c = h[t];
    base_s[t] = c ? atomicAdd(&dcur[t], c) : 0;
    h[t] = 0;
  }
  __syncthreads();
  for (int r = base + threadIdx.x; r < end; r += 256){
    int c = cnt[r];
    int b = min(c, DBINS - 1);
    int pos = base_s[b] + atomicAdd(&h[b], 1);
    int bg = offs[r];
    rd[n - 1 - pos] = make_int4(bg, bg + c, r, 0);   // descending degree
  }
}

// ---------------- fp8 helpers (gfx950 HW cvt; encode/decode self-consistent) ----------------

__device__ __forceinline__ unsigned pack4_fp8(float a, float b, float c, float d){
  int p = 0;
  p = __builtin_amdgcn_cvt_pk_fp8_f32(a, b, p, false);   // bytes 0,1
  p = __builtin_amdgcn_cvt_pk_fp8_f32(c, d, p, true);    // bytes 2,3
  return (unsigned)p;
}

__device__ __forceinline__ void accq(float* a, uint2 q){
  v2f f0 = __builtin_amdgcn_cvt_pk_f32_fp8(q.x, false);
  v2f f1 = __builtin_amdgcn_cvt_pk_f32_fp8(q.x, true);
  v2f f2 = __builtin_amdgcn_cvt_pk_f32_fp8(q.y, false);
  v2f f3 = __builtin_amdgcn_cvt_pk_f32_fp8(q.y, true);
  a[0] += f0.x; a[1] += f0.y; a[2] += f1.x; a[3] += f1.y;
  a[4] += f2.x; a[5] += f2.y; a[6] += f3.x; a[7] += f3.y;
}

// ---------------- fused init: out = 0.25*emb ; fp8 tables = emb * pre-scale * S ----------------

__global__ void init_k(const float* __restrict__ ue, const float* __restrict__ ie,
                       const float* __restrict__ dus, const float* __restrict__ dis,
                       float* __restrict__ out, unsigned char* __restrict__ ue8,
                       unsigned char* __restrict__ ie8){
  int idx4 = blockIdx.x * blockDim.x + threadIdx.x;   // one float4 per thread
  const int nu4 = U_NUM * (EMB / 4);
  const int tot4 = (U_NUM + I_NUM) * (EMB / 4);
  if (idx4 >= tot4) return;
  const float* e; unsigned char* hp; float s; int loc;
  if (idx4 < nu4){ e = ue; hp = ue8; loc = idx4; s = dus[idx4 >> 4] * FP8_SCALE; }
  else { e = ie; hp = ie8; loc = idx4 - nu4; s = dis[(idx4 - nu4) >> 4] * FP8_SCALE; }
  float4 v = ((const float4*)e)[loc];
  float4 o = make_float4(v.x * 0.25f, v.y * 0.25f, v.z * 0.25f, v.w * 0.25f);
  ((float4*)out)[idx4] = o;
  ((unsigned*)hp)[loc] = pack4_fp8(v.x * s, v.y * s, v.z * s, v.w * s);
}

// ---------------- fp8 gather SpMM, paired (two independent SpMMs per launch) ----------------
// 8 lanes per row, each lane owns 8 fp8 (8 B) -> one uint2 gather per edge per
// lane (row = 64 B, fully contiguous). fp32 accumulate. Tables carry a global
// x512 scale that propagates through the chain; removed only in the fp32 sum
// epilogue. rd is degree-DESCENDING. Epilogue: dst8[row] = fp8(acc * ph[row]);
// if HAS_SUM: sum[row] += acc * ps[row] * 0.25/512.

template<bool HAS_SUM>
__global__ void spmm_pair(
    const int4* __restrict__ rdA, const int* __restrict__ adjA,
    const unsigned char* __restrict__ srcA, const float* __restrict__ psA, const float* __restrict__ phA,
    unsigned char* __restrict__ dstA, float* __restrict__ sumA, int nA,
    const int4* __restrict__ rdB, const int* __restrict__ adjB,
    const unsigned char* __restrict__ srcB, const float* __restrict__ psB, const float* __restrict__ phB,
    unsigned char* __restrict__ dstB, float* __restrict__ sumB, int nB){
  int t = blockIdx.x * blockDim.x + threadIdx.x;
  int rid = t >> 3;
  int lane = t & 7;
  const int4* rd; const int* adj; const unsigned char* src; const float* ps; const float* ph;
  unsigned char* dst; float* sum;
  if (rid < nA){
    rd = rdA; adj = adjA; src = srcA; ps = psA; ph = phA; dst = dstA; sum = sumA;
  } else {
    rid -= nA;
    if (rid >= nB) return;
    rd = rdB; adj = adjB; src = srcB; ps = psB; ph = phB; dst = dstB; sum = sumB;
  }
  int4 d = rd[rid];
  int beg = d.x, end = d.y, row = d.z;
  const unsigned char* sp8 = src + (size_t)(lane << 3);   // lane's 8-B slice base
  float acc[8];
#pragma unroll
  for (int k = 0; k < 8; ++k) acc[k] = 0.f;
  int j = beg;
  for (; j + 7 < end; j += 8){
    int n0 = adj[j],   n1 = adj[j+1], n2 = adj[j+2], n3 = adj[j+3];
    int n4 = adj[j+4], n5 = adj[j+5], n6 = adj[j+6], n7 = adj[j+7];
    uint2 q0 = *(const uint2*)(sp8 + (((size_t)n0) << 6));
    uint2 q1 = *(const uint2*)(sp8 + (((size_t)n1) << 6));
    uint2 q2 = *(const uint2*)(sp8 + (((size_t)n2) << 6));
    uint2 q3 = *(const uint2*)(sp8 + (((size_t)n3) << 6));
    uint2 q4 = *(const uint2*)(sp8 + (((size_t)n4) << 6));
    uint2 q5 = *(const uint2*)(sp8 + (((size_t)n5) << 6));
    uint2 q6 = *(const uint2*)(sp8 + (((size_t)n6) << 6));
    uint2 q7 = *(const uint2*)(sp8 + (((size_t)n7) << 6));
    accq(acc, q0); accq(acc, q1); accq(acc, q2); accq(acc, q3);
    accq(acc, q4); accq(acc, q5); accq(acc, q6); accq(acc, q7);
  }
  for (; j < end; ++j){
    int n0 = adj[j];
    uint2 q0 = *(const uint2*)(sp8 + (((size_t)n0) << 6));
    accq(acc, q0);
  }
  float phv = ph[row];
  unsigned lo = pack4_fp8(acc[0] * phv, acc[1] * phv, acc[2] * phv, acc[3] * phv);
  unsigned hi = pack4_fp8(acc[4] * phv, acc[5] * phv, acc[6] * phv, acc[7] * phv);
  *(uint2*)(dst + (((size_t)row) << 6) + (size_t)(lane << 3)) = make_uint2(lo, hi);
  if (HAS_SUM){
    float psv = ps[row] * (0.25f / FP8_SCALE);
    float4* sp = (float4*)(sum + (((size_t)row) << 6) + (size_t)(lane << 3));
#pragma unroll
    for (int k = 0; k < 2; ++k){
      float4 s = sp[k];
      s.x += acc[4*k]     * psv;
      s.y += acc[4*k + 1] * psv;
      s.z += acc[4*k + 2] * psv;
      s.w += acc[4*k + 3] * psv;
      sp[k] = s;
    }
  }
}

// ---------------- driver ----------------

extern "C" void kernel_launch(void* const* d_in, const int* in_sizes, int n_in,
                              void* d_out, int out_size, void* d_ws, size_t ws_size,
                              hipStream_t stream){
  const float* user_emb = (const float*)d_in[0];
  const float* item_emb = (const float*)d_in[1];
  const int*   u_idx    = (const int*)d_in[2];
  const int*   i_idx    = (const int*)d_in[3];
  float* out = (float*)d_out;

  char* w = (char*)d_ws;
  size_t off = 0;
  auto alloc = [&](size_t bytes) -> void* {
    void* p = (void*)(w + off);
    off += (bytes + 255) & ~(size_t)255;
    return p;
  };
  int* cnt_u   = (int*)alloc((size_t)U_NUM * 4);
  int* cnt_i   = (int*)alloc((size_t)I_NUM * 4);
  int* offs_u  = (int*)alloc((size_t)(U_NUM + 1) * 4);
  int* offs_i  = (int*)alloc((size_t)(I_NUM + 1) * 4);
  int* cm_u    = (int*)alloc((size_t)NBLK_E * NBU_U * 4);
  int* cm_i    = (int*)alloc((size_t)NBLK_E * NBU_I * 4);
  int* bm_u    = (int*)alloc((size_t)NBLK_E * NBU_U * 4);
  int* bm_i    = (int*)alloc((size_t)NBLK_E * NBU_I * 4);
  int* tot_u   = (int*)alloc((size_t)NBU_U * 4);
  int* tot_i   = (int*)alloc((size_t)NBU_I * 4);
  int* boffs_u = (int*)alloc((size_t)(NBU_U + 1) * 4);
  int* boffs_i = (int*)alloc((size_t)(NBU_I + 1) * 4);
  int* scr_u   = (int*)alloc((size_t)NBU_U * 4);     // small_scan cur scratch
  int* scr_i   = (int*)alloc((size_t)NBU_I * 4);
  int* dhist_u = (int*)alloc((size_t)DBINS * 4);
  int* dhist_i = (int*)alloc((size_t)DBINS * 4);
  int* doffs_u = (int*)alloc((size_t)(DBINS + 1) * 4);
  int* doffs_i = (int*)alloc((size_t)(DBINS + 1) * 4);
  int* dcur_u  = (int*)alloc((size_t)DBINS * 4);
  int* dcur_i  = (int*)alloc((size_t)DBINS * 4);
  int4* rd_u   = (int4*)alloc((size_t)U_NUM * 16);   // {beg,end,row,0} desc-degree
  int4* rd_i   = (int4*)alloc((size_t)I_NUM * 16);
  int* adj_u   = (int*)alloc((size_t)NE * 4);
  int* adj_i   = (int*)alloc((size_t)NE * 4);
  float* du_inv  = (float*)alloc((size_t)U_NUM * 4);
  float* du_invs = (float*)alloc((size_t)U_NUM * 4);
  float* di_inv  = (float*)alloc((size_t)I_NUM * 4);
  float* di_invs = (float*)alloc((size_t)I_NUM * 4);
  // fp8 table region, 19.2 MB; the packed bins (16 MB) alias its start and
  // are dead before init_k writes the tables.
  unsigned char* hreg = (unsigned char*)alloc((size_t)(U_NUM + I_NUM) * 128);
  unsigned char* ue8    = hreg;                                 // U_NUM*64 B
  unsigned char* ie8    = ue8    + (size_t)U_NUM * EMB;         // I_NUM*64 B
  unsigned char* tmp_i8 = ie8    + (size_t)I_NUM * EMB;         // I_NUM*64 B
  unsigned char* tmp_u8 = tmp_i8 + (size_t)I_NUM * EMB;         // U_NUM*64 B
  int* bin_u = (int*)hreg;            // NE ints (8 MB)
  int* bin_i = bin_u + NE;            // NE ints (8 MB)

  // ---- CSR build (count-matrix radix sort) ----
  hist_k<<<NBLK_E, 256, 0, stream>>>(u_idx, i_idx, cm_u, cm_i, dhist_u, dhist_i);
  colsum_k<<<NBU_T, 256, 0, stream>>>(cm_u, cm_i, tot_u, tot_i);
  small_scan2_k<<<2, 1024, 0, stream>>>(tot_u, boffs_u, scr_u, NBU_U,
                                        tot_i, boffs_i, scr_i, NBU_I);
  colscan_k<<<NBU_T, 256, 0, stream>>>(cm_u, cm_i, boffs_u, boffs_i, bm_u, bm_i);
  binfill_k<<<NBLK_E, 256, 0, stream>>>(u_idx, i_idx, bm_u, bm_i, bin_u, bin_i);
  bucket_build_k<<<NBU_T, 256, 0, stream>>>(bin_u, bin_i, boffs_u, boffs_i,
                                            cnt_u, cnt_i, offs_u, offs_i,
                                            du_inv, du_invs, di_inv, di_invs,
                                            adj_u, adj_i, dhist_u, dhist_i);

  // ---- degree sort (descending rowdesc) ----
  small_scan2_k<<<2, 1024, 0, stream>>>(dhist_u, doffs_u, dcur_u, DBINS,
                                        dhist_i, doffs_i, dcur_i, DBINS);
  deg_scatter_k<<<ceil_div(U_NUM, 2048), 256, 0, stream>>>(cnt_u, offs_u, dcur_u, rd_u, U_NUM);
  deg_scatter_k<<<ceil_div(I_NUM, 2048), 256, 0, stream>>>(cnt_i, offs_i, dcur_i, rd_i, I_NUM);

  // ---- propagation (fp8 tables, fp32 accumulation) ----
  init_k<<<ceil_div((U_NUM + I_NUM) * EMB / 4, 256), 256, 0, stream>>>(
      user_emb, item_emb, du_invs, di_invs, out, ue8, ie8);

  float* sum_u = out;
  float* sum_i = out + (size_t)U_NUM * EMB;
  const int pair_grid = ceil_div((U_NUM + I_NUM) * 8, 256);
  for (int l = 0; l < NLAYERS; ++l){
    // A: tmp_i8 = fp8(d_i_inv * R^T ue8)   +   C: tmp_u8 = fp8(d_u_inv * R ie8)
    spmm_pair<false><<<pair_grid, 256, 0, stream>>>(
        rd_i, adj_i, ue8, nullptr, di_inv, tmp_i8, nullptr, I_NUM,
        rd_u, adj_u, ie8, nullptr, du_inv, tmp_u8, nullptr, U_NUM);
    // B: sum_u += 0.25*du_invs * R tmp_i8 ; ue8 = fp8(du_inv * R tmp_i8)
    // D: sum_i += 0.25*di_invs * R^T tmp_u8 ; ie8 = fp8(di_inv * R^T tmp_u8)
    spmm_pair<true><<<pair_grid, 256, 0, stream>>>(
        rd_u, adj_u, tmp_i8, du_invs, du_inv, ue8, sum_u, U_NUM,
        rd_i, adj_i, tmp_u8, di_invs, di_inv, ie8, sum_i, I_NUM);
  }
}

// Round 7
// 489.732 us; speedup vs baseline: 1.3428x; 1.0523x over previous
//
#include <hip/hip_runtime.h>
#include <hip/hip_fp16.h>
#include <math.h>

#define U_NUM 100000
#define I_NUM 50000
#define NE    2000000
#define EMB   64
#define NLAYERS 3

// bucketing: 512 rows per bucket
#define BSH   9
#define BROWS 512
#define NBU_U ((U_NUM + 511) >> 9)   // 196
#define NBU_I ((I_NUM + 511) >> 9)   // 98
#define NBU_T (NBU_U + NBU_I)        // 294
#define CHUNK 8192
#define NBLK_E ((NE + CHUNK - 1) / CHUNK)   // 245  (must stay <= 256 for colscan_k)
#define DBINS 512
#define PACK_SH 17
#define PACK_MASK 0x1FFFF

// deg-scatter / init fused-kernel block ranges
#define ND_U ((U_NUM + 2047) / 2048)   // 49
#define ND_I ((I_NUM + 2047) / 2048)   // 25
#define NINIT (((U_NUM + I_NUM) * (EMB / 4) + 255) / 256)   // 9375

// fp8 table scale: values ~1e-3..1e-2 are below e4m3's sweet range; S lifts
// them to ~0.5..8. S propagates through the SpMM chain transparently; only
// init (*S) and the final merge (0.25/S) touch it.
#define FP8_SCALE 512.0f

typedef float v2f __attribute__((ext_vector_type(2)));

static inline int ceil_div(int a, int b){ return (a + b - 1) / b; }

// ---------------- phase 1: per-block bucket counts ----------------
// blocks 0-3 also zero the degree histograms / cursors (saves memset launches)

__global__ void hist_k(const int* __restrict__ u_idx, const int* __restrict__ i_idx,
                       int* __restrict__ cm_u, int* __restrict__ cm_i,
                       int* __restrict__ dhist_u, int* __restrict__ dhist_i,
                       int* __restrict__ dcur_u, int* __restrict__ dcur_i){
  if (blockIdx.x == 0){
    for (int t = threadIdx.x; t < DBINS; t += 256) dhist_u[t] = 0;
  } else if (blockIdx.x == 1){
    for (int t = threadIdx.x; t < DBINS; t += 256) dhist_i[t] = 0;
  } else if (blockIdx.x == 2){
    for (int t = threadIdx.x; t < DBINS; t += 256) dcur_u[t] = 0;
  } else if (blockIdx.x == 3){
    for (int t = threadIdx.x; t < DBINS; t += 256) dcur_i[t] = 0;
  }
  __shared__ int h[NBU_T];
  for (int t = threadIdx.x; t < NBU_T; t += 256) h[t] = 0;
  __syncthreads();
  int base = blockIdx.x * CHUNK;
  int end = min(base + CHUNK, NE);
  for (int e = base + (threadIdx.x << 1); e < end; e += 512){
    int2 uu = *(const int2*)(u_idx + e);
    int2 ii = *(const int2*)(i_idx + e);
    atomicAdd(&h[uu.x >> BSH], 1);
    atomicAdd(&h[uu.y >> BSH], 1);
    atomicAdd(&h[NBU_U + (ii.x >> BSH)], 1);
    atomicAdd(&h[NBU_U + (ii.y >> BSH)], 1);
  }
  __syncthreads();
  for (int t = threadIdx.x; t < NBU_U; t += 256) cm_u[blockIdx.x * NBU_U + t] = h[t];
  for (int t = threadIdx.x; t < NBU_I; t += 256) cm_i[blockIdx.x * NBU_I + t] = h[NBU_U + t];
}

// column sums of the count matrices -> per-bucket totals
__global__ void colsum_k(const int* __restrict__ cm_u, const int* __restrict__ cm_i,
                         int* __restrict__ tot_u, int* __restrict__ tot_i){
  __shared__ int s[256];
  int j = blockIdx.x;
  const int* cm; int* tot; int jj, stride;
  if (j < NBU_U){ cm = cm_u; tot = tot_u; jj = j; stride = NBU_U; }
  else { cm = cm_i; tot = tot_i; jj = j - NBU_U; stride = NBU_I; }
  int acc = 0;
  for (int b = threadIdx.x; b < NBLK_E; b += 256) acc += cm[b * stride + jj];
  s[threadIdx.x] = acc; __syncthreads();
  for (int o = 128; o > 0; o >>= 1){
    if (threadIdx.x < o) s[threadIdx.x] += s[threadIdx.x + o];
    __syncthreads();
  }
  if (threadIdx.x == 0) tot[jj] = s[0];
}

// per-bucket column scan; each block also derives its own bucket offset
// boffs[jj] = sum(tot[0..jj-1]) in-kernel (kills the separate scan launch)
__global__ void colscan_k(const int* __restrict__ cm_u, const int* __restrict__ cm_i,
                          const int* __restrict__ tot_u, const int* __restrict__ tot_i,
                          int* __restrict__ boffs_u, int* __restrict__ boffs_i,
                          int* __restrict__ bm_u, int* __restrict__ bm_i){
  __shared__ int s[256];
  __shared__ int red[256];
  __shared__ int bj;
  int j = blockIdx.x;
  const int* cm; const int* tot; int* boffs; int* bm; int jj, stride, nbu;
  if (j < NBU_U){ cm = cm_u; tot = tot_u; boffs = boffs_u; bm = bm_u; jj = j; stride = NBU_U; nbu = NBU_U; }
  else { cm = cm_i; tot = tot_i; boffs = boffs_i; bm = bm_i; jj = j - NBU_U; stride = NBU_I; nbu = NBU_I; }
  int t = threadIdx.x;
  int my = 0;
  for (int k = t; k < jj; k += 256) my += tot[k];
  red[t] = my; __syncthreads();
  for (int o = 128; o > 0; o >>= 1){
    if (t < o) red[t] += red[t + o];
    __syncthreads();
  }
  if (t == 0){
    bj = red[0];
    boffs[jj] = red[0];
    if (jj == nbu - 1) boffs[nbu] = red[0] + tot[jj];
  }
  int v = (t < NBLK_E) ? cm[t * stride + jj] : 0;
  s[t] = v; __syncthreads();           // also publishes bj
  for (int o = 1; o < 256; o <<= 1){
    int x = (t >= o) ? s[t - o] : 0;
    __syncthreads();
    s[t] += x;
    __syncthreads();
  }
  int excl = (t > 0) ? s[t - 1] : 0;
  if (t < NBLK_E) bm[t * stride + jj] = excl + bj;
}

// ---------------- phase 2: scatter edges into bucket-sorted bins ----------------
// packed bin entry: (row_local << 17) | neighbor  (row_local < 512, neighbor < 2^17)

__global__ void binfill_k(const int* __restrict__ u_idx, const int* __restrict__ i_idx,
                          const int* __restrict__ bm_u, const int* __restrict__ bm_i,
                          int* __restrict__ bin_u, int* __restrict__ bin_i){
  __shared__ int cur[NBU_T];
  for (int t = threadIdx.x; t < NBU_U; t += 256) cur[t] = bm_u[blockIdx.x * NBU_U + t];
  for (int t = threadIdx.x; t < NBU_I; t += 256) cur[NBU_U + t] = bm_i[blockIdx.x * NBU_I + t];
  __syncthreads();
  int base = blockIdx.x * CHUNK;
  int end = min(base + CHUNK, NE);
  for (int e = base + (threadIdx.x << 1); e < end; e += 512){
    int2 uu = *(const int2*)(u_idx + e);
    int2 ii = *(const int2*)(i_idx + e);
    int p;
    p = atomicAdd(&cur[uu.x >> BSH], 1);            bin_u[p] = ((uu.x & 511) << PACK_SH) | ii.x;
    p = atomicAdd(&cur[uu.y >> BSH], 1);            bin_u[p] = ((uu.y & 511) << PACK_SH) | ii.y;
    p = atomicAdd(&cur[NBU_U + (ii.x >> BSH)], 1);  bin_i[p] = ((ii.x & 511) << PACK_SH) | uu.x;
    p = atomicAdd(&cur[NBU_U + (ii.y >> BSH)], 1);  bin_i[p] = ((ii.y & 511) << PACK_SH) | uu.y;
  }
}

// ---------------- phase 3: per-bucket CSR build ----------------

__global__ void bucket_build_k(const int* __restrict__ bin_u, const int* __restrict__ bin_i,
                               const int* __restrict__ boffs_u, const int* __restrict__ boffs_i,
                               int* __restrict__ cnt_u, int* __restrict__ cnt_i,
                               int* __restrict__ offs_u, int* __restrict__ offs_i,
                               float* __restrict__ du_inv, float* __restrict__ du_invs,
                               float* __restrict__ di_inv, float* __restrict__ di_invs,
                               int* __restrict__ adj_u, int* __restrict__ adj_i,
                               int* __restrict__ dhist_u, int* __restrict__ dhist_i){
  __shared__ int h[BROWS];
  __shared__ int part[256];
  __shared__ int dh[DBINS];
  int b = blockIdx.x;
  const int* bin; const int* boffs; int* cnt; int* offs; float* inv; float* invs;
  int* adj; int* dhist; int jj, nrows;
  if (b < NBU_U){
    bin = bin_u; boffs = boffs_u; cnt = cnt_u; offs = offs_u;
    inv = du_inv; invs = du_invs; adj = adj_u; dhist = dhist_u; jj = b; nrows = U_NUM;
  } else {
    bin = bin_i; boffs = boffs_i; cnt = cnt_i; offs = offs_i;
    inv = di_inv; invs = di_invs; adj = adj_i; dhist = dhist_i; jj = b - NBU_U; nrows = I_NUM;
  }
  int tid = threadIdx.x;
  int r0 = jj << BSH;
  int beg = boffs[jj], end = boffs[jj + 1];
  h[2*tid] = 0; h[2*tid + 1] = 0;
  for (int t = tid; t < DBINS; t += 256) dh[t] = 0;
  __syncthreads();
  for (int e = beg + tid; e < end; e += 256)
    atomicAdd(&h[((unsigned)bin[e]) >> PACK_SH], 1);
  __syncthreads();
  int c0 = h[2*tid], c1 = h[2*tid + 1];
  part[tid] = c0 + c1; __syncthreads();
  for (int o = 1; o < 256; o <<= 1){
    int x = (tid >= o) ? part[tid - o] : 0;
    __syncthreads();
    part[tid] += x;
    __syncthreads();
  }
  int excl = (tid > 0) ? part[tid - 1] : 0;
  h[2*tid] = excl;
  h[2*tid + 1] = excl + c0;
#pragma unroll
  for (int k = 0; k < 2; ++k){
    int l = 2*tid + k;
    int row = r0 + l;
    int c = k ? c1 : c0;
    int o = k ? (excl + c0) : excl;
    if (row < nrows){
      cnt[row] = c;
      offs[row] = beg + o;
      float d = (c > 0) ? (float)c : 1.0f;
      inv[row]  = 1.0f / d;
      invs[row] = 1.0f / sqrtf(d);
      atomicAdd(&dh[min(c, DBINS - 1)], 1);
    } else if (row == nrows){
      offs[row] = beg + o;   // global sentinel
    }
  }
  __syncthreads();
  for (int e = beg + tid; e < end; e += 256){
    int v = bin[e];
    int slot = beg + atomicAdd(&h[((unsigned)v) >> PACK_SH], 1);
    adj[slot] = v & PACK_MASK;
  }
  __syncthreads();
  for (int t = tid; t < DBINS; t += 256) if (dh[t]) atomicAdd(&dhist[t], dh[t]);
}

// ---------------- fp8 helpers (gfx950 HW cvt; encode/decode self-consistent) ----------------

__device__ __forceinline__ unsigned pack4_fp8(float a, float b, float c, float d){
  int p = 0;
  p = __builtin_amdgcn_cvt_pk_fp8_f32(a, b, p, false);   // bytes 0,1
  p = __builtin_amdgcn_cvt_pk_fp8_f32(c, d, p, true);    // bytes 2,3
  return (unsigned)p;
}

__device__ __forceinline__ void accq(float* a, uint2 q){
  v2f f0 = __builtin_amdgcn_cvt_pk_f32_fp8(q.x, false);
  v2f f1 = __builtin_amdgcn_cvt_pk_f32_fp8(q.x, true);
  v2f f2 = __builtin_amdgcn_cvt_pk_f32_fp8(q.y, false);
  v2f f3 = __builtin_amdgcn_cvt_pk_f32_fp8(q.y, true);
  a[0] += f0.x; a[1] += f0.y; a[2] += f1.x; a[3] += f1.y;
  a[4] += f2.x; a[5] += f2.y; a[6] += f3.x; a[7] += f3.y;
}

// ---------------- fused post-CSR kernel: deg-scatter (u,i) + init ----------------
// deg blocks self-scan the degree histogram (512 bins) in LDS and use
// zero-initialized cursors for intra-bin bases -> no separate scan launch.
// init blocks: out = 0.25*emb ; u0/i0 fp8 tables = emb * pre-scale * S.

__global__ void post_k(const int* __restrict__ cnt_u, const int* __restrict__ offs_u,
                       const int* __restrict__ dhist_u, int* __restrict__ dcur_u,
                       int4* __restrict__ rd_u,
                       const int* __restrict__ cnt_i, const int* __restrict__ offs_i,
                       const int* __restrict__ dhist_i, int* __restrict__ dcur_i,
                       int4* __restrict__ rd_i,
                       const float* __restrict__ ue, const float* __restrict__ ie,
                       const float* __restrict__ dus, const float* __restrict__ dis,
                       float* __restrict__ out, unsigned char* __restrict__ u0,
                       unsigned char* __restrict__ i0){
  int b = blockIdx.x;
  int t = threadIdx.x;
  if (b >= ND_U + ND_I){
    // ---- init part ----
    int idx4 = (b - ND_U - ND_I) * 256 + t;
    const int nu4 = U_NUM * (EMB / 4);
    const int tot4 = (U_NUM + I_NUM) * (EMB / 4);
    if (idx4 >= tot4) return;
    const float* e; unsigned char* hp; float s; int loc;
    if (idx4 < nu4){ e = ue; hp = u0; loc = idx4; s = dus[idx4 >> 4] * FP8_SCALE; }
    else { e = ie; hp = i0; loc = idx4 - nu4; s = dis[(idx4 - nu4) >> 4] * FP8_SCALE; }
    float4 v = ((const float4*)e)[loc];
    ((float4*)out)[idx4] = make_float4(v.x * 0.25f, v.y * 0.25f, v.z * 0.25f, v.w * 0.25f);
    ((unsigned*)hp)[loc] = pack4_fp8(v.x * s, v.y * s, v.z * s, v.w * s);
    return;
  }
  // ---- degree scatter part ----
  const int* cnt; const int* offs; const int* dhist; int* dcur; int4* rd; int n, base;
  if (b < ND_U){ cnt = cnt_u; offs = offs_u; dhist = dhist_u; dcur = dcur_u; rd = rd_u; n = U_NUM; base = b * 2048; }
  else { cnt = cnt_i; offs = offs_i; dhist = dhist_i; dcur = dcur_i; rd = rd_i; n = I_NUM; base = (b - ND_U) * 2048; }
  __shared__ int sc[DBINS];
  __shared__ int h[DBINS];
  __shared__ int base_s[DBINS];
  sc[t] = dhist[t]; sc[t + 256] = dhist[t + 256];
  h[t] = 0; h[t + 256] = 0;
  __syncthreads();
  for (int o = 1; o < DBINS; o <<= 1){
    int x0 = (t >= o) ? sc[t - o] : 0;
    int x1 = ((t + 256) >= o) ? sc[t + 256 - o] : 0;
    __syncthreads();
    sc[t] += x0; sc[t + 256] += x1;
    __syncthreads();
  }
  int end = min(base + 2048, n);
  for (int r = base + t; r < end; r += 256)
    atomicAdd(&h[min(cnt[r], DBINS - 1)], 1);
  __syncthreads();
  for (int tt = t; tt < DBINS; tt += 256){
    int c = h[tt];
    int excl = tt ? sc[tt - 1] : 0;
    base_s[tt] = c ? (excl + atomicAdd(&dcur[tt], c)) : 0;
    h[tt] = 0;
  }
  __syncthreads();
  for (int r = base + t; r < end; r += 256){
    int c = cnt[r];
    int bb = min(c, DBINS - 1);
    int pos = base_s[bb] + atomicAdd(&h[bb], 1);
    int bg = offs[r];
    rd[n - 1 - pos] = make_int4(bg, bg + c, r, 0);   // descending degree
  }
}

// ---------------- fp8 gather SpMM, paired, NO sum epilogue ----------------
// 8 lanes per row, one uint2 (8 B) gather per edge per lane; fp32 accumulate;
// dst8[row] = fp8(acc * ph[row]). Sum accumulation is DEFERRED to merge_k
// (kills the 77 MB/launch sum RMW in the former HAS_SUM launches).

__global__ void spmm_pair(
    const int4* __restrict__ rdA, const int* __restrict__ adjA,
    const unsigned char* __restrict__ srcA, const float* __restrict__ phA,
    unsigned char* __restrict__ dstA, int nA,
    const int4* __restrict__ rdB, const int* __restrict__ adjB,
    const unsigned char* __restrict__ srcB, const float* __restrict__ phB,
    unsigned char* __restrict__ dstB, int nB){
  int t = blockIdx.x * blockDim.x + threadIdx.x;
  int rid = t >> 3;
  int lane = t & 7;
  const int4* rd; const int* adj; const unsigned char* src; const float* ph;
  unsigned char* dst;
  if (rid < nA){
    rd = rdA; adj = adjA; src = srcA; ph = phA; dst = dstA;
  } else {
    rid -= nA;
    if (rid >= nB) return;
    rd = rdB; adj = adjB; src = srcB; ph = phB; dst = dstB;
  }
  int4 d = rd[rid];
  int beg = d.x, end = d.y, row = d.z;
  const unsigned char* sp8 = src + (size_t)(lane << 3);
  float acc[8];
#pragma unroll
  for (int k = 0; k < 8; ++k) acc[k] = 0.f;
  int j = beg;
  for (; j + 7 < end; j += 8){
    int n0 = adj[j],   n1 = adj[j+1], n2 = adj[j+2], n3 = adj[j+3];
    int n4 = adj[j+4], n5 = adj[j+5], n6 = adj[j+6], n7 = adj[j+7];
    uint2 q0 = *(const uint2*)(sp8 + (((size_t)n0) << 6));
    uint2 q1 = *(const uint2*)(sp8 + (((size_t)n1) << 6));
    uint2 q2 = *(const uint2*)(sp8 + (((size_t)n2) << 6));
    uint2 q3 = *(const uint2*)(sp8 + (((size_t)n3) << 6));
    uint2 q4 = *(const uint2*)(sp8 + (((size_t)n4) << 6));
    uint2 q5 = *(const uint2*)(sp8 + (((size_t)n5) << 6));
    uint2 q6 = *(const uint2*)(sp8 + (((size_t)n6) << 6));
    uint2 q7 = *(const uint2*)(sp8 + (((size_t)n7) << 6));
    accq(acc, q0); accq(acc, q1); accq(acc, q2); accq(acc, q3);
    accq(acc, q4); accq(acc, q5); accq(acc, q6); accq(acc, q7);
  }
  for (; j < end; ++j){
    int n0 = adj[j];
    uint2 q0 = *(const uint2*)(sp8 + (((size_t)n0) << 6));
    accq(acc, q0);
  }
  float phv = ph[row];
  unsigned lo = pack4_fp8(acc[0] * phv, acc[1] * phv, acc[2] * phv, acc[3] * phv);
  unsigned hi = pack4_fp8(acc[4] * phv, acc[5] * phv, acc[6] * phv, acc[7] * phv);
  *(uint2*)(dst + (((size_t)row) << 6) + (size_t)(lane << 3)) = make_uint2(lo, hi);
}

// ---------------- final merge: out += sum_l 0.25*(invs/inv)/S * deq(table_l) ----------------

__global__ void merge_k(const unsigned char* __restrict__ u1, const unsigned char* __restrict__ u2,
                        const unsigned char* __restrict__ u3,
                        const unsigned char* __restrict__ i1, const unsigned char* __restrict__ i2,
                        const unsigned char* __restrict__ i3,
                        const float* __restrict__ du_inv, const float* __restrict__ du_invs,
                        const float* __restrict__ di_inv, const float* __restrict__ di_invs,
                        float* __restrict__ out){
  int idx4 = blockIdx.x * blockDim.x + threadIdx.x;   // one float4 / 4 fp8 per thread
  const int nu4 = U_NUM * (EMB / 4);
  const int tot4 = (U_NUM + I_NUM) * (EMB / 4);
  if (idx4 >= tot4) return;
  const unsigned char *t1, *t2, *t3; float ratio; int loc;
  if (idx4 < nu4){
    t1 = u1; t2 = u2; t3 = u3; loc = idx4;
    int row = idx4 >> 4;
    ratio = (0.25f / FP8_SCALE) * du_invs[row] / du_inv[row];
  } else {
    loc = idx4 - nu4;
    t1 = i1; t2 = i2; t3 = i3;
    int row = loc >> 4;
    ratio = (0.25f / FP8_SCALE) * di_invs[row] / di_inv[row];
  }
  unsigned q1 = ((const unsigned*)t1)[loc];
  unsigned q2 = ((const unsigned*)t2)[loc];
  unsigned q3 = ((const unsigned*)t3)[loc];
  float4 o = ((float4*)out)[idx4];
  v2f a, b;
  a = __builtin_amdgcn_cvt_pk_f32_fp8(q1, false); b = __builtin_amdgcn_cvt_pk_f32_fp8(q1, true);
  o.x += ratio * a.x; o.y += ratio * a.y; o.z += ratio * b.x; o.w += ratio * b.y;
  a = __builtin_amdgcn_cvt_pk_f32_fp8(q2, false); b = __builtin_amdgcn_cvt_pk_f32_fp8(q2, true);
  o.x += ratio * a.x; o.y += ratio * a.y; o.z += ratio * b.x; o.w += ratio * b.y;
  a = __builtin_amdgcn_cvt_pk_f32_fp8(q3, false); b = __builtin_amdgcn_cvt_pk_f32_fp8(q3, true);
  o.x += ratio * a.x; o.y += ratio * a.y; o.z += ratio * b.x; o.w += ratio * b.y;
  ((float4*)out)[idx4] = o;
}

// ---------------- driver ----------------

extern "C" void kernel_launch(void* const* d_in, const int* in_sizes, int n_in,
                              void* d_out, int out_size, void* d_ws, size_t ws_size,
                              hipStream_t stream){
  const float* user_emb = (const float*)d_in[0];
  const float* item_emb = (const float*)d_in[1];
  const int*   u_idx    = (const int*)d_in[2];
  const int*   i_idx    = (const int*)d_in[3];
  float* out = (float*)d_out;

  char* w = (char*)d_ws;
  size_t off = 0;
  auto alloc = [&](size_t bytes) -> void* {
    void* p = (void*)(w + off);
    off += (bytes + 255) & ~(size_t)255;
    return p;
  };
  int* cnt_u   = (int*)alloc((size_t)U_NUM * 4);
  int* cnt_i   = (int*)alloc((size_t)I_NUM * 4);
  int* offs_u  = (int*)alloc((size_t)(U_NUM + 1) * 4);
  int* offs_i  = (int*)alloc((size_t)(I_NUM + 1) * 4);
  int* cm_u    = (int*)alloc((size_t)NBLK_E * NBU_U * 4);
  int* cm_i    = (int*)alloc((size_t)NBLK_E * NBU_I * 4);
  int* bm_u    = (int*)alloc((size_t)NBLK_E * NBU_U * 4);
  int* bm_i    = (int*)alloc((size_t)NBLK_E * NBU_I * 4);
  int* tot_u   = (int*)alloc((size_t)NBU_U * 4);
  int* tot_i   = (int*)alloc((size_t)NBU_I * 4);
  int* boffs_u = (int*)alloc((size_t)(NBU_U + 1) * 4);
  int* boffs_i = (int*)alloc((size_t)(NBU_I + 1) * 4);
  int* dhist_u = (int*)alloc((size_t)DBINS * 4);
  int* dhist_i = (int*)alloc((size_t)DBINS * 4);
  int* dcur_u  = (int*)alloc((size_t)DBINS * 4);
  int* dcur_i  = (int*)alloc((size_t)DBINS * 4);
  int4* rd_u   = (int4*)alloc((size_t)U_NUM * 16);   // {beg,end,row,0} desc-degree
  int4* rd_i   = (int4*)alloc((size_t)I_NUM * 16);
  int* adj_u   = (int*)alloc((size_t)NE * 4);
  int* adj_i   = (int*)alloc((size_t)NE * 4);
  float* du_inv  = (float*)alloc((size_t)U_NUM * 4);
  float* du_invs = (float*)alloc((size_t)U_NUM * 4);
  float* di_inv  = (float*)alloc((size_t)I_NUM * 4);
  float* di_invs = (float*)alloc((size_t)I_NUM * 4);
  // fp8 table region: per-layer ping-pong snapshots (u0..u3, i0..i3) + tmp;
  // the packed bins (16 MB) alias its start and are dead before post_k
  // writes u0 (and all other tables are written later still).
  const size_t URB = (size_t)U_NUM * EMB;   // 6.4 MB per user table
  const size_t IRB = (size_t)I_NUM * EMB;   // 3.2 MB per item table
  unsigned char* hreg = (unsigned char*)alloc(4 * URB + 4 * IRB + URB + IRB);
  unsigned char* u0 = hreg;
  unsigned char* u1 = u0 + URB;
  unsigned char* u2 = u1 + URB;
  unsigned char* u3 = u2 + URB;
  unsigned char* i0 = u3 + URB;
  unsigned char* i1 = i0 + IRB;
  unsigned char* i2 = i1 + IRB;
  unsigned char* i3 = i2 + IRB;
  unsigned char* tmp_i = i3 + IRB;          // I_NUM*64
  unsigned char* tmp_u = tmp_i + IRB;       // U_NUM*64
  int* bin_u = (int*)hreg;            // NE ints (8 MB)
  int* bin_i = bin_u + NE;            // NE ints (8 MB)

  // ---- CSR build ----
  hist_k<<<NBLK_E, 256, 0, stream>>>(u_idx, i_idx, cm_u, cm_i, dhist_u, dhist_i, dcur_u, dcur_i);
  colsum_k<<<NBU_T, 256, 0, stream>>>(cm_u, cm_i, tot_u, tot_i);
  colscan_k<<<NBU_T, 256, 0, stream>>>(cm_u, cm_i, tot_u, tot_i,
                                       boffs_u, boffs_i, bm_u, bm_i);
  binfill_k<<<NBLK_E, 256, 0, stream>>>(u_idx, i_idx, bm_u, bm_i, bin_u, bin_i);
  bucket_build_k<<<NBU_T, 256, 0, stream>>>(bin_u, bin_i, boffs_u, boffs_i,
                                            cnt_u, cnt_i, offs_u, offs_i,
                                            du_inv, du_invs, di_inv, di_invs,
                                            adj_u, adj_i, dhist_u, dhist_i);

  // ---- fused degree-scatter + init ----
  post_k<<<ND_U + ND_I + NINIT, 256, 0, stream>>>(
      cnt_u, offs_u, dhist_u, dcur_u, rd_u,
      cnt_i, offs_i, dhist_i, dcur_i, rd_i,
      user_emb, item_emb, du_invs, di_invs, out, u0, i0);

  // ---- propagation (fp8 tables, fp32 accumulation, deferred sum) ----
  const int pair_grid = ceil_div((U_NUM + I_NUM) * 8, 256);
  unsigned char* uls[4] = { u0, u1, u2, u3 };
  unsigned char* ils[4] = { i0, i1, i2, i3 };
  for (int l = 0; l < NLAYERS; ++l){
    // A: tmp_i = fp8(d_i_inv * R^T u_l)   +   C: tmp_u = fp8(d_u_inv * R i_l)
    spmm_pair<<<pair_grid, 256, 0, stream>>>(
        rd_i, adj_i, uls[l], di_inv, tmp_i, I_NUM,
        rd_u, adj_u, ils[l], du_inv, tmp_u, U_NUM);
    // B: u_{l+1} = fp8(d_u_inv * R tmp_i) ; D: i_{l+1} = fp8(d_i_inv * R^T tmp_u)
    spmm_pair<<<pair_grid, 256, 0, stream>>>(
        rd_u, adj_u, tmp_i, du_inv, uls[l + 1], U_NUM,
        rd_i, adj_i, tmp_u, di_inv, ils[l + 1], I_NUM);
  }

  // ---- final merge: fold the three layer terms into out ----
  merge_k<<<NINIT, 256, 0, stream>>>(u1, u2, u3, i1, i2, i3,
                                     du_inv, du_invs, di_inv, di_invs, out);
}

// Round 8
// 488.426 us; speedup vs baseline: 1.3464x; 1.0027x over previous
//
#include <hip/hip_runtime.h>
#include <hip/hip_fp16.h>
#include <math.h>

#define U_NUM 100000
#define I_NUM 50000
#define NE    2000000
#define EMB   64
#define NLAYERS 3

// bucketing: 128 rows per bucket (R7: 512-row buckets -> only 294 blocks in
// bucket_build_k -> 6.9% occupancy, 57 us; 128 rows -> 1173 blocks)
#define BSH   7
#define BROWS 128
#define NBU_U ((U_NUM + BROWS - 1) >> BSH)   // 782
#define NBU_I ((I_NUM + BROWS - 1) >> BSH)   // 391
#define NBU_T (NBU_U + NBU_I)                // 1173
#define CHUNK 8192
#define NBLK_E ((NE + CHUNK - 1) / CHUNK)    // 245  (must stay <= 256 for colscan_k)
#define DBINS 512
#define PACK_SH 17
#define PACK_MASK 0x1FFFF

// deg-scatter / init fused-kernel block ranges
#define ND_U ((U_NUM + 2047) / 2048)   // 49
#define ND_I ((I_NUM + 2047) / 2048)   // 25
#define NINIT (((U_NUM + I_NUM) * (EMB / 4) + 255) / 256)   // 9375

// fp8 table scale: values ~1e-3..1e-2 are below e4m3's sweet range; S lifts
// them to ~0.5..8. S propagates through the SpMM chain transparently; only
// init (*S) and the final merge (0.25/S) touch it.
#define FP8_SCALE 512.0f

typedef float v2f __attribute__((ext_vector_type(2)));

static inline int ceil_div(int a, int b){ return (a + b - 1) / b; }

// ---------------- phase 1: per-block bucket counts ----------------
// blocks 0-3 also zero the degree histograms / cursors (saves memset launches)

__global__ void hist_k(const int* __restrict__ u_idx, const int* __restrict__ i_idx,
                       int* __restrict__ cm_u, int* __restrict__ cm_i,
                       int* __restrict__ dhist_u, int* __restrict__ dhist_i,
                       int* __restrict__ dcur_u, int* __restrict__ dcur_i){
  if (blockIdx.x == 0){
    for (int t = threadIdx.x; t < DBINS; t += 256) dhist_u[t] = 0;
  } else if (blockIdx.x == 1){
    for (int t = threadIdx.x; t < DBINS; t += 256) dhist_i[t] = 0;
  } else if (blockIdx.x == 2){
    for (int t = threadIdx.x; t < DBINS; t += 256) dcur_u[t] = 0;
  } else if (blockIdx.x == 3){
    for (int t = threadIdx.x; t < DBINS; t += 256) dcur_i[t] = 0;
  }
  __shared__ int h[NBU_T];
  for (int t = threadIdx.x; t < NBU_T; t += 256) h[t] = 0;
  __syncthreads();
  int base = blockIdx.x * CHUNK;
  int end = min(base + CHUNK, NE);
  for (int e = base + (threadIdx.x << 1); e < end; e += 512){
    int2 uu = *(const int2*)(u_idx + e);
    int2 ii = *(const int2*)(i_idx + e);
    atomicAdd(&h[uu.x >> BSH], 1);
    atomicAdd(&h[uu.y >> BSH], 1);
    atomicAdd(&h[NBU_U + (ii.x >> BSH)], 1);
    atomicAdd(&h[NBU_U + (ii.y >> BSH)], 1);
  }
  __syncthreads();
  for (int t = threadIdx.x; t < NBU_U; t += 256) cm_u[blockIdx.x * NBU_U + t] = h[t];
  for (int t = threadIdx.x; t < NBU_I; t += 256) cm_i[blockIdx.x * NBU_I + t] = h[NBU_U + t];
}

// column sums of the count matrices -> per-bucket totals
__global__ void colsum_k(const int* __restrict__ cm_u, const int* __restrict__ cm_i,
                         int* __restrict__ tot_u, int* __restrict__ tot_i){
  __shared__ int s[256];
  int j = blockIdx.x;
  const int* cm; int* tot; int jj, stride;
  if (j < NBU_U){ cm = cm_u; tot = tot_u; jj = j; stride = NBU_U; }
  else { cm = cm_i; tot = tot_i; jj = j - NBU_U; stride = NBU_I; }
  int acc = 0;
  for (int b = threadIdx.x; b < NBLK_E; b += 256) acc += cm[b * stride + jj];
  s[threadIdx.x] = acc; __syncthreads();
  for (int o = 128; o > 0; o >>= 1){
    if (threadIdx.x < o) s[threadIdx.x] += s[threadIdx.x + o];
    __syncthreads();
  }
  if (threadIdx.x == 0) tot[jj] = s[0];
}

// per-bucket column scan; each block also derives its own bucket offset
// boffs[jj] = sum(tot[0..jj-1]) in-kernel (kills the separate scan launch)
__global__ void colscan_k(const int* __restrict__ cm_u, const int* __restrict__ cm_i,
                          const int* __restrict__ tot_u, const int* __restrict__ tot_i,
                          int* __restrict__ boffs_u, int* __restrict__ boffs_i,
                          int* __restrict__ bm_u, int* __restrict__ bm_i){
  __shared__ int s[256];
  __shared__ int red[256];
  __shared__ int bj;
  int j = blockIdx.x;
  const int* cm; const int* tot; int* boffs; int* bm; int jj, stride, nbu;
  if (j < NBU_U){ cm = cm_u; tot = tot_u; boffs = boffs_u; bm = bm_u; jj = j; stride = NBU_U; nbu = NBU_U; }
  else { cm = cm_i; tot = tot_i; boffs = boffs_i; bm = bm_i; jj = j - NBU_U; stride = NBU_I; nbu = NBU_I; }
  int t = threadIdx.x;
  int my = 0;
  for (int k = t; k < jj; k += 256) my += tot[k];
  red[t] = my; __syncthreads();
  for (int o = 128; o > 0; o >>= 1){
    if (t < o) red[t] += red[t + o];
    __syncthreads();
  }
  if (t == 0){
    bj = red[0];
    boffs[jj] = red[0];
    if (jj == nbu - 1) boffs[nbu] = red[0] + tot[jj];
  }
  int v = (t < NBLK_E) ? cm[t * stride + jj] : 0;
  s[t] = v; __syncthreads();           // also publishes bj
  for (int o = 1; o < 256; o <<= 1){
    int x = (t >= o) ? s[t - o] : 0;
    __syncthreads();
    s[t] += x;
    __syncthreads();
  }
  int excl = (t > 0) ? s[t - 1] : 0;
  if (t < NBLK_E) bm[t * stride + jj] = excl + bj;
}

// ---------------- phase 2: scatter edges into bucket-sorted bins ----------------
// packed bin entry: (row_local << 17) | neighbor  (row_local < 128, neighbor < 2^17)

__global__ void binfill_k(const int* __restrict__ u_idx, const int* __restrict__ i_idx,
                          const int* __restrict__ bm_u, const int* __restrict__ bm_i,
                          int* __restrict__ bin_u, int* __restrict__ bin_i){
  __shared__ int cur[NBU_T];
  for (int t = threadIdx.x; t < NBU_U; t += 256) cur[t] = bm_u[blockIdx.x * NBU_U + t];
  for (int t = threadIdx.x; t < NBU_I; t += 256) cur[NBU_U + t] = bm_i[blockIdx.x * NBU_I + t];
  __syncthreads();
  int base = blockIdx.x * CHUNK;
  int end = min(base + CHUNK, NE);
  for (int e = base + (threadIdx.x << 1); e < end; e += 512){
    int2 uu = *(const int2*)(u_idx + e);
    int2 ii = *(const int2*)(i_idx + e);
    int p;
    p = atomicAdd(&cur[uu.x >> BSH], 1);            bin_u[p] = ((uu.x & (BROWS-1)) << PACK_SH) | ii.x;
    p = atomicAdd(&cur[uu.y >> BSH], 1);            bin_u[p] = ((uu.y & (BROWS-1)) << PACK_SH) | ii.y;
    p = atomicAdd(&cur[NBU_U + (ii.x >> BSH)], 1);  bin_i[p] = ((ii.x & (BROWS-1)) << PACK_SH) | uu.x;
    p = atomicAdd(&cur[NBU_U + (ii.y >> BSH)], 1);  bin_i[p] = ((ii.y & (BROWS-1)) << PACK_SH) | uu.y;
  }
}

// ---------------- phase 3: per-bucket CSR build (one row per thread) ----------------

__global__ void bucket_build_k(const int* __restrict__ bin_u, const int* __restrict__ bin_i,
                               const int* __restrict__ boffs_u, const int* __restrict__ boffs_i,
                               int* __restrict__ cnt_u, int* __restrict__ cnt_i,
                               int* __restrict__ offs_u, int* __restrict__ offs_i,
                               float* __restrict__ du_inv, float* __restrict__ du_invs,
                               float* __restrict__ di_inv, float* __restrict__ di_invs,
                               int* __restrict__ adj_u, int* __restrict__ adj_i,
                               int* __restrict__ dhist_u, int* __restrict__ dhist_i){
  __shared__ int h[BROWS];
  __shared__ int part[256];
  __shared__ int dh[DBINS];
  int b = blockIdx.x;
  const int* bin; const int* boffs; int* cnt; int* offs; float* inv; float* invs;
  int* adj; int* dhist; int jj, nrows;
  if (b < NBU_U){
    bin = bin_u; boffs = boffs_u; cnt = cnt_u; offs = offs_u;
    inv = du_inv; invs = du_invs; adj = adj_u; dhist = dhist_u; jj = b; nrows = U_NUM;
  } else {
    bin = bin_i; boffs = boffs_i; cnt = cnt_i; offs = offs_i;
    inv = di_inv; invs = di_invs; adj = adj_i; dhist = dhist_i; jj = b - NBU_U; nrows = I_NUM;
  }
  int tid = threadIdx.x;
  int r0 = jj << BSH;
  int beg = boffs[jj], end = boffs[jj + 1];
  if (tid < BROWS) h[tid] = 0;
  for (int t = tid; t < DBINS; t += 256) dh[t] = 0;
  __syncthreads();
  for (int e = beg + tid; e < end; e += 256)
    atomicAdd(&h[((unsigned)bin[e]) >> PACK_SH], 1);
  __syncthreads();
  int c = (tid < BROWS) ? h[tid] : 0;
  part[tid] = c; __syncthreads();
  for (int o = 1; o < 256; o <<= 1){
    int x = (tid >= o) ? part[tid - o] : 0;
    __syncthreads();
    part[tid] += x;
    __syncthreads();
  }
  int excl = (tid > 0) ? part[tid - 1] : 0;
  if (tid < BROWS){
    h[tid] = excl;                      // cursor base for scatter
    int row = r0 + tid;
    if (row < nrows){
      cnt[row] = c;
      offs[row] = beg + excl;
      float d = (c > 0) ? (float)c : 1.0f;
      inv[row]  = 1.0f / d;
      invs[row] = 1.0f / sqrtf(d);
      atomicAdd(&dh[min(c, DBINS - 1)], 1);
    } else if (row == nrows){
      offs[row] = beg + excl;           // global sentinel (== NE in last bucket)
    }
  }
  __syncthreads();
  for (int e = beg + tid; e < end; e += 256){
    int v = bin[e];
    int slot = beg + atomicAdd(&h[((unsigned)v) >> PACK_SH], 1);
    adj[slot] = v & PACK_MASK;
  }
  __syncthreads();
  for (int t = tid; t < DBINS; t += 256) if (dh[t]) atomicAdd(&dhist[t], dh[t]);
}

// ---------------- fp8 helpers (gfx950 HW cvt; encode/decode self-consistent) ----------------

__device__ __forceinline__ unsigned pack4_fp8(float a, float b, float c, float d){
  int p = 0;
  p = __builtin_amdgcn_cvt_pk_fp8_f32(a, b, p, false);   // bytes 0,1
  p = __builtin_amdgcn_cvt_pk_fp8_f32(c, d, p, true);    // bytes 2,3
  return (unsigned)p;
}

__device__ __forceinline__ void accq(float* a, uint2 q){
  v2f f0 = __builtin_amdgcn_cvt_pk_f32_fp8(q.x, false);
  v2f f1 = __builtin_amdgcn_cvt_pk_f32_fp8(q.x, true);
  v2f f2 = __builtin_amdgcn_cvt_pk_f32_fp8(q.y, false);
  v2f f3 = __builtin_amdgcn_cvt_pk_f32_fp8(q.y, true);
  a[0] += f0.x; a[1] += f0.y; a[2] += f1.x; a[3] += f1.y;
  a[4] += f2.x; a[5] += f2.y; a[6] += f3.x; a[7] += f3.y;
}

// ---------------- fused post-CSR kernel: deg-scatter (u,i) + init ----------------
// deg blocks self-scan the degree histogram (512 bins) in LDS and use
// zero-initialized cursors for intra-bin bases -> no separate scan launch.
// init blocks: out = 0.25*emb ; u0/i0 fp8 tables = emb * pre-scale * S.

__global__ void post_k(const int* __restrict__ cnt_u, const int* __restrict__ offs_u,
                       const int* __restrict__ dhist_u, int* __restrict__ dcur_u,
                       int4* __restrict__ rd_u,
                       const int* __restrict__ cnt_i, const int* __restrict__ offs_i,
                       const int* __restrict__ dhist_i, int* __restrict__ dcur_i,
                       int4* __restrict__ rd_i,
                       const float* __restrict__ ue, const float* __restrict__ ie,
                       const float* __restrict__ dus, const float* __restrict__ dis,
                       float* __restrict__ out, unsigned char* __restrict__ u0,
                       unsigned char* __restrict__ i0){
  int b = blockIdx.x;
  int t = threadIdx.x;
  if (b >= ND_U + ND_I){
    // ---- init part ----
    int idx4 = (b - ND_U - ND_I) * 256 + t;
    const int nu4 = U_NUM * (EMB / 4);
    const int tot4 = (U_NUM + I_NUM) * (EMB / 4);
    if (idx4 >= tot4) return;
    const float* e; unsigned char* hp; float s; int loc;
    if (idx4 < nu4){ e = ue; hp = u0; loc = idx4; s = dus[idx4 >> 4] * FP8_SCALE; }
    else { e = ie; hp = i0; loc = idx4 - nu4; s = dis[(idx4 - nu4) >> 4] * FP8_SCALE; }
    float4 v = ((const float4*)e)[loc];
    ((float4*)out)[idx4] = make_float4(v.x * 0.25f, v.y * 0.25f, v.z * 0.25f, v.w * 0.25f);
    ((unsigned*)hp)[loc] = pack4_fp8(v.x * s, v.y * s, v.z * s, v.w * s);
    return;
  }
  // ---- degree scatter part ----
  const int* cnt; const int* offs; const int* dhist; int* dcur; int4* rd; int n, base;
  if (b < ND_U){ cnt = cnt_u; offs = offs_u; dhist = dhist_u; dcur = dcur_u; rd = rd_u; n = U_NUM; base = b * 2048; }
  else { cnt = cnt_i; offs = offs_i; dhist = dhist_i; dcur = dcur_i; rd = rd_i; n = I_NUM; base = (b - ND_U) * 2048; }
  __shared__ int sc[DBINS];
  __shared__ int h[DBINS];
  __shared__ int base_s[DBINS];
  sc[t] = dhist[t]; sc[t + 256] = dhist[t + 256];
  h[t] = 0; h[t + 256] = 0;
  __syncthreads();
  for (int o = 1; o < DBINS; o <<= 1){
    int x0 = (t >= o) ? sc[t - o] : 0;
    int x1 = ((t + 256) >= o) ? sc[t + 256 - o] : 0;
    __syncthreads();
    sc[t] += x0; sc[t + 256] += x1;
    __syncthreads();
  }
  int end = min(base + 2048, n);
  for (int r = base + t; r < end; r += 256)
    atomicAdd(&h[min(cnt[r], DBINS - 1)], 1);
  __syncthreads();
  for (int tt = t; tt < DBINS; tt += 256){
    int c = h[tt];
    int excl = tt ? sc[tt - 1] : 0;
    base_s[tt] = c ? (excl + atomicAdd(&dcur[tt], c)) : 0;
    h[tt] = 0;
  }
  __syncthreads();
  for (int r = base + t; r < end; r += 256){
    int c = cnt[r];
    int bb = min(c, DBINS - 1);
    int pos = base_s[bb] + atomicAdd(&h[bb], 1);
    int bg = offs[r];
    rd[n - 1 - pos] = make_int4(bg, bg + c, r, 0);   // descending degree
  }
}

// ---------------- fp8 gather SpMM, paired, NO sum epilogue ----------------
// 8 lanes per row, one uint2 (8 B) gather per edge per lane; fp32 accumulate;
// dst8[row] = fp8(acc * ph[row]). Sum accumulation is DEFERRED to merge_k.

__global__ void spmm_pair(
    const int4* __restrict__ rdA, const int* __restrict__ adjA,
    const unsigned char* __restrict__ srcA, const float* __restrict__ phA,
    unsigned char* __restrict__ dstA, int nA,
    const int4* __restrict__ rdB, const int* __restrict__ adjB,
    const unsigned char* __restrict__ srcB, const float* __restrict__ phB,
    unsigned char* __restrict__ dstB, int nB){
  int t = blockIdx.x * blockDim.x + threadIdx.x;
  int rid = t >> 3;
  int lane = t & 7;
  const int4* rd; const int* adj; const unsigned char* src; const float* ph;
  unsigned char* dst;
  if (rid < nA){
    rd = rdA; adj = adjA; src = srcA; ph = phA; dst = dstA;
  } else {
    rid -= nA;
    if (rid >= nB) return;
    rd = rdB; adj = adjB; src = srcB; ph = phB; dst = dstB;
  }
  int4 d = rd[rid];
  int beg = d.x, end = d.y, row = d.z;
  const unsigned char* sp8 = src + (size_t)(lane << 3);
  float acc[8];
#pragma unroll
  for (int k = 0; k < 8; ++k) acc[k] = 0.f;
  int j = beg;
  for (; j + 7 < end; j += 8){
    int n0 = adj[j],   n1 = adj[j+1], n2 = adj[j+2], n3 = adj[j+3];
    int n4 = adj[j+4], n5 = adj[j+5], n6 = adj[j+6], n7 = adj[j+7];
    uint2 q0 = *(const uint2*)(sp8 + (((size_t)n0) << 6));
    uint2 q1 = *(const uint2*)(sp8 + (((size_t)n1) << 6));
    uint2 q2 = *(const uint2*)(sp8 + (((size_t)n2) << 6));
    uint2 q3 = *(const uint2*)(sp8 + (((size_t)n3) << 6));
    uint2 q4 = *(const uint2*)(sp8 + (((size_t)n4) << 6));
    uint2 q5 = *(const uint2*)(sp8 + (((size_t)n5) << 6));
    uint2 q6 = *(const uint2*)(sp8 + (((size_t)n6) << 6));
    uint2 q7 = *(const uint2*)(sp8 + (((size_t)n7) << 6));
    accq(acc, q0); accq(acc, q1); accq(acc, q2); accq(acc, q3);
    accq(acc, q4); accq(acc, q5); accq(acc, q6); accq(acc, q7);
  }
  for (; j < end; ++j){
    int n0 = adj[j];
    uint2 q0 = *(const uint2*)(sp8 + (((size_t)n0) << 6));
    accq(acc, q0);
  }
  float phv = ph[row];
  unsigned lo = pack4_fp8(acc[0] * phv, acc[1] * phv, acc[2] * phv, acc[3] * phv);
  unsigned hi = pack4_fp8(acc[4] * phv, acc[5] * phv, acc[6] * phv, acc[7] * phv);
  *(uint2*)(dst + (((size_t)row) << 6) + (size_t)(lane << 3)) = make_uint2(lo, hi);
}

// ---------------- final merge: out += sum_l 0.25*(invs/inv)/S * deq(table_l) ----------------

__global__ void merge_k(const unsigned char* __restrict__ u1, const unsigned char* __restrict__ u2,
                        const unsigned char* __restrict__ u3,
                        const unsigned char* __restrict__ i1, const unsigned char* __restrict__ i2,
                        const unsigned char* __restrict__ i3,
                        const float* __restrict__ du_inv, const float* __restrict__ du_invs,
                        const float* __restrict__ di_inv, const float* __restrict__ di_invs,
                        float* __restrict__ out){
  int idx4 = blockIdx.x * blockDim.x + threadIdx.x;   // one float4 / 4 fp8 per thread
  const int nu4 = U_NUM * (EMB / 4);
  const int tot4 = (U_NUM + I_NUM) * (EMB / 4);
  if (idx4 >= tot4) return;
  const unsigned char *t1, *t2, *t3; float ratio; int loc;
  if (idx4 < nu4){
    t1 = u1; t2 = u2; t3 = u3; loc = idx4;
    int row = idx4 >> 4;
    ratio = (0.25f / FP8_SCALE) * du_invs[row] / du_inv[row];
  } else {
    loc = idx4 - nu4;
    t1 = i1; t2 = i2; t3 = i3;
    int row = loc >> 4;
    ratio = (0.25f / FP8_SCALE) * di_invs[row] / di_inv[row];
  }
  unsigned q1 = ((const unsigned*)t1)[loc];
  unsigned q2 = ((const unsigned*)t2)[loc];
  unsigned q3 = ((const unsigned*)t3)[loc];
  float4 o = ((float4*)out)[idx4];
  v2f a, b;
  a = __builtin_amdgcn_cvt_pk_f32_fp8(q1, false); b = __builtin_amdgcn_cvt_pk_f32_fp8(q1, true);
  o.x += ratio * a.x; o.y += ratio * a.y; o.z += ratio * b.x; o.w += ratio * b.y;
  a = __builtin_amdgcn_cvt_pk_f32_fp8(q2, false); b = __builtin_amdgcn_cvt_pk_f32_fp8(q2, true);
  o.x += ratio * a.x; o.y += ratio * a.y; o.z += ratio * b.x; o.w += ratio * b.y;
  a = __builtin_amdgcn_cvt_pk_f32_fp8(q3, false); b = __builtin_amdgcn_cvt_pk_f32_fp8(q3, true);
  o.x += ratio * a.x; o.y += ratio * a.y; o.z += ratio * b.x; o.w += ratio * b.y;
  ((float4*)out)[idx4] = o;
}

// ---------------- driver ----------------

extern "C" void kernel_launch(void* const* d_in, const int* in_sizes, int n_in,
                              void* d_out, int out_size, void* d_ws, size_t ws_size,
                              hipStream_t stream){
  const float* user_emb = (const float*)d_in[0];
  const float* item_emb = (const float*)d_in[1];
  const int*   u_idx    = (const int*)d_in[2];
  const int*   i_idx    = (const int*)d_in[3];
  float* out = (float*)d_out;

  char* w = (char*)d_ws;
  size_t off = 0;
  auto alloc = [&](size_t bytes) -> void* {
    void* p = (void*)(w + off);
    off += (bytes + 255) & ~(size_t)255;
    return p;
  };
  int* cnt_u   = (int*)alloc((size_t)U_NUM * 4);
  int* cnt_i   = (int*)alloc((size_t)I_NUM * 4);
  int* offs_u  = (int*)alloc((size_t)(U_NUM + 1) * 4);
  int* offs_i  = (int*)alloc((size_t)(I_NUM + 1) * 4);
  int* cm_u    = (int*)alloc((size_t)NBLK_E * NBU_U * 4);
  int* cm_i    = (int*)alloc((size_t)NBLK_E * NBU_I * 4);
  int* bm_u    = (int*)alloc((size_t)NBLK_E * NBU_U * 4);
  int* bm_i    = (int*)alloc((size_t)NBLK_E * NBU_I * 4);
  int* tot_u   = (int*)alloc((size_t)NBU_U * 4);
  int* tot_i   = (int*)alloc((size_t)NBU_I * 4);
  int* boffs_u = (int*)alloc((size_t)(NBU_U + 1) * 4);
  int* boffs_i = (int*)alloc((size_t)(NBU_I + 1) * 4);
  int* dhist_u = (int*)alloc((size_t)DBINS * 4);
  int* dhist_i = (int*)alloc((size_t)DBINS * 4);
  int* dcur_u  = (int*)alloc((size_t)DBINS * 4);
  int* dcur_i  = (int*)alloc((size_t)DBINS * 4);
  int4* rd_u   = (int4*)alloc((size_t)U_NUM * 16);   // {beg,end,row,0} desc-degree
  int4* rd_i   = (int4*)alloc((size_t)I_NUM * 16);
  int* adj_u   = (int*)alloc((size_t)NE * 4);
  int* adj_i   = (int*)alloc((size_t)NE * 4);
  float* du_inv  = (float*)alloc((size_t)U_NUM * 4);
  float* du_invs = (float*)alloc((size_t)U_NUM * 4);
  float* di_inv  = (float*)alloc((size_t)I_NUM * 4);
  float* di_invs = (float*)alloc((size_t)I_NUM * 4);
  // fp8 table region: per-layer ping-pong snapshots (u0..u3, i0..i3) + tmp;
  // the packed bins (16 MB) alias its start and are dead before post_k
  // writes u0 (and all other tables are written later still).
  const size_t URB = (size_t)U_NUM * EMB;   // 6.4 MB per user table
  const size_t IRB = (size_t)I_NUM * EMB;   // 3.2 MB per item table
  unsigned char* hreg = (unsigned char*)alloc(4 * URB + 4 * IRB + URB + IRB);
  unsigned char* u0 = hreg;
  unsigned char* u1 = u0 + URB;
  unsigned char* u2 = u1 + URB;
  unsigned char* u3 = u2 + URB;
  unsigned char* i0 = u3 + URB;
  unsigned char* i1 = i0 + IRB;
  unsigned char* i2 = i1 + IRB;
  unsigned char* i3 = i2 + IRB;
  unsigned char* tmp_i = i3 + IRB;          // I_NUM*64
  unsigned char* tmp_u = tmp_i + IRB;       // U_NUM*64
  int* bin_u = (int*)hreg;            // NE ints (8 MB)
  int* bin_i = bin_u + NE;            // NE ints (8 MB)

  // ---- CSR build ----
  hist_k<<<NBLK_E, 256, 0, stream>>>(u_idx, i_idx, cm_u, cm_i, dhist_u, dhist_i, dcur_u, dcur_i);
  colsum_k<<<NBU_T, 256, 0, stream>>>(cm_u, cm_i, tot_u, tot_i);
  colscan_k<<<NBU_T, 256, 0, stream>>>(cm_u, cm_i, tot_u, tot_i,
                                       boffs_u, boffs_i, bm_u, bm_i);
  binfill_k<<<NBLK_E, 256, 0, stream>>>(u_idx, i_idx, bm_u, bm_i, bin_u, bin_i);
  bucket_build_k<<<NBU_T, 256, 0, stream>>>(bin_u, bin_i, boffs_u, boffs_i,
                                            cnt_u, cnt_i, offs_u, offs_i,
                                            du_inv, du_invs, di_inv, di_invs,
                                            adj_u, adj_i, dhist_u, dhist_i);

  // ---- fused degree-scatter + init ----
  post_k<<<ND_U + ND_I + NINIT, 256, 0, stream>>>(
      cnt_u, offs_u, dhist_u, dcur_u, rd_u,
      cnt_i, offs_i, dhist_i, dcur_i, rd_i,
      user_emb, item_emb, du_invs, di_invs, out, u0, i0);

  // ---- propagation (fp8 tables, fp32 accumulation, deferred sum) ----
  const int pair_grid = ceil_div((U_NUM + I_NUM) * 8, 256);
  unsigned char* uls[4] = { u0, u1, u2, u3 };
  unsigned char* ils[4] = { i0, i1, i2, i3 };
  for (int l = 0; l < NLAYERS; ++l){
    // A: tmp_i = fp8(d_i_inv * R^T u_l)   +   C: tmp_u = fp8(d_u_inv * R i_l)
    spmm_pair<<<pair_grid, 256, 0, stream>>>(
        rd_i, adj_i, uls[l], di_inv, tmp_i, I_NUM,
        rd_u, adj_u, ils[l], du_inv, tmp_u, U_NUM);
    // B: u_{l+1} = fp8(d_u_inv * R tmp_i) ; D: i_{l+1} = fp8(d_i_inv * R^T tmp_u)
    spmm_pair<<<pair_grid, 256, 0, stream>>>(
        rd_u, adj_u, tmp_i, du_inv, uls[l + 1], U_NUM,
        rd_i, adj_i, tmp_u, di_inv, ils[l + 1], I_NUM);
  }

  // ---- final merge: fold the three layer terms into out ----
  merge_k<<<NINIT, 256, 0, stream>>>(u1, u2, u3, i1, i2, i3,
                                     du_inv, du_invs, di_inv, di_invs, out);
}